// Round 13
// baseline (41842.572 us; speedup 1.0000x reference)
//
#include <hip/hip_runtime.h>
#include <stdint.h>
#include <stddef.h>

#define BB 32
#define TT 64
#define DD 512
#define HH 8
#define HDIM 64
#define LL 4
#define FFD 2048
#define VV 128

#define NBLK 512
#define NTHR 512

// ---------------- threefry2x32 (20 rounds), matches JAX ----------------
__host__ __device__ inline uint32_t rotl32(uint32_t v, int n){ return (v << n) | (v >> (32 - n)); }

__host__ __device__ inline void tf2x32(uint32_t k0, uint32_t k1, uint32_t x0, uint32_t x1,
                                       uint32_t* o0, uint32_t* o1){
  uint32_t ks2 = k0 ^ k1 ^ 0x1BD11BDAu;
  x0 += k0; x1 += k1;
  x0 += x1; x1 = rotl32(x1,13); x1 ^= x0;
  x0 += x1; x1 = rotl32(x1,15); x1 ^= x0;
  x0 += x1; x1 = rotl32(x1,26); x1 ^= x0;
  x0 += x1; x1 = rotl32(x1, 6); x1 ^= x0;
  x0 += k1; x1 += ks2 + 1u;
  x0 += x1; x1 = rotl32(x1,17); x1 ^= x0;
  x0 += x1; x1 = rotl32(x1,29); x1 ^= x0;
  x0 += x1; x1 = rotl32(x1,16); x1 ^= x0;
  x0 += x1; x1 = rotl32(x1,24); x1 ^= x0;
  x0 += ks2; x1 += k0 + 2u;
  x0 += x1; x1 = rotl32(x1,13); x1 ^= x0;
  x0 += x1; x1 = rotl32(x1,15); x1 ^= x0;
  x0 += x1; x1 = rotl32(x1,26); x1 ^= x0;
  x0 += x1; x1 = rotl32(x1, 6); x1 ^= x0;
  x0 += k0; x1 += k1 + 3u;
  x0 += x1; x1 = rotl32(x1,17); x1 ^= x0;
  x0 += x1; x1 = rotl32(x1,29); x1 ^= x0;
  x0 += x1; x1 = rotl32(x1,16); x1 ^= x0;
  x0 += x1; x1 = rotl32(x1,24); x1 ^= x0;
  x0 += k1; x1 += ks2 + 4u;
  x0 += x1; x1 = rotl32(x1,13); x1 ^= x0;
  x0 += x1; x1 = rotl32(x1,15); x1 ^= x0;
  x0 += x1; x1 = rotl32(x1,26); x1 ^= x0;
  x0 += x1; x1 = rotl32(x1, 6); x1 ^= x0;
  x0 += ks2; x1 += k0 + 5u;
  *o0 = x0; *o1 = x1;
}

// ---------------- helpers ----------------
__device__ inline float dot_f4(const float* __restrict__ a, const float* __restrict__ w, int K){
  float acc = 0.f;
  const float4* a4 = (const float4*)a;
  const float4* w4 = (const float4*)w;
  int K4 = K >> 2;
  for (int k = 0; k < K4; ++k){
    float4 av = a4[k], wv = w4[k];
    acc = fmaf(av.x, wv.x, acc);
    acc = fmaf(av.y, wv.y, acc);
    acc = fmaf(av.z, wv.z, acc);
    acc = fmaf(av.w, wv.w, acc);
  }
  return acc;
}

// LayerNorm across a 512-thread block (one value per thread).
__device__ inline float block_ln(float v, float g, float bb, float* red){
  __syncthreads();
  float s = v;
  #pragma unroll
  for (int off = 32; off; off >>= 1) s += __shfl_xor(s, off);
  if ((threadIdx.x & 63) == 0) red[threadIdx.x >> 6] = s;
  __syncthreads();
  float mu = (red[0]+red[1]+red[2]+red[3]+red[4]+red[5]+red[6]+red[7]) * (1.0f/512.0f);
  float dv = v - mu;
  float sq = dv * dv;
  #pragma unroll
  for (int off = 32; off; off >>= 1) sq += __shfl_xor(sq, off);
  __syncthreads();
  if ((threadIdx.x & 63) == 0) red[threadIdx.x >> 6] = sq;
  __syncthreads();
  float var = (red[0]+red[1]+red[2]+red[3]+red[4]+red[5]+red[6]+red[7]) * (1.0f/512.0f);
  return dv * (1.0f / sqrtf(var + 1e-5f)) * g + bb;
}

// row reduction among the 128 threads (2 waves) owning row j; all 512 threads call.
__device__ inline float row_reduce(float v, int wid, int j, float* wred){
  #pragma unroll
  for (int off = 32; off; off >>= 1) v += __shfl_xor(v, off);
  if ((threadIdx.x & 63) == 0) wred[wid] = v;
  __syncthreads();
  float r = wred[2*j] + wred[2*j+1];
  __syncthreads();
  return r;
}

// ---------------- group barrier: 64 blocks of group g ----------------
__device__ __forceinline__ void gbar(unsigned* bar, int g){
  __syncthreads();
  if (threadIdx.x == 0){
    unsigned* cnt = bar + g*64;
    unsigned* gen = bar + g*64 + 16;
    __builtin_amdgcn_fence(__ATOMIC_RELEASE, "agent");
    unsigned old = __hip_atomic_load(gen, __ATOMIC_RELAXED, __HIP_MEMORY_SCOPE_AGENT);
    if (__hip_atomic_fetch_add(cnt, 1u, __ATOMIC_RELAXED, __HIP_MEMORY_SCOPE_AGENT) == 63u){
      __hip_atomic_store(cnt, 0u, __ATOMIC_RELAXED, __HIP_MEMORY_SCOPE_AGENT);
      __hip_atomic_fetch_add(gen, 1u, __ATOMIC_RELEASE, __HIP_MEMORY_SCOPE_AGENT);
    } else {
      while (__hip_atomic_load(gen, __ATOMIC_RELAXED, __HIP_MEMORY_SCOPE_AGENT) == old)
        __builtin_amdgcn_s_sleep(1);
    }
    __builtin_amdgcn_fence(__ATOMIC_ACQUIRE, "agent");
  }
  __syncthreads();
}

// ---------------- setup kernels ----------------
__global__ void k_tables(float* __restrict__ cosb, float* __restrict__ sinb){
  int tid = blockIdx.x * blockDim.x + threadIdx.x;  // TT*256
  int p = tid >> 8, i = tid & 255;
  float sv = (2.0f * (float)i + 204.8f) / 716.8f;
  float scale = powf(sv, (float)p / 16.0f);
  float invf = 1.0f / powf(10000.0f, (float)i / 256.0f);
  float ang = (float)p * invf;
  cosb[tid] = cosf(ang) * scale;
  sinb[tid] = sinf(ang) * scale;
}

__global__ void k_ca1(const float* __restrict__ mol, const float* __restrict__ w,
                      const float* __restrict__ bias, float* __restrict__ tmp){
  int tid = blockIdx.x * blockDim.x + threadIdx.x;  // LL*BB*DD
  int l = tid >> 14; int r = tid & 16383; int b = r >> 9; int d = r & 511;
  const float* wr = w + (size_t)l*3*DD*DD + (size_t)(2*DD + d)*DD;
  tmp[tid] = bias[l*3*DD + 2*DD + d] + dot_f4(mol + (size_t)b*DD, wr, DD);
}

__global__ void k_ca2(const float* __restrict__ tmp, const float* __restrict__ w,
                      const float* __restrict__ bias, float* __restrict__ cac){
  int tid = blockIdx.x * blockDim.x + threadIdx.x;  // LL*BB*DD
  int l = tid >> 14; int r = tid & 16383; int b = r >> 9; int d = r & 511;
  const float* wr = w + (size_t)l*DD*DD + (size_t)d*DD;
  cac[tid] = bias[l*DD + d] + dot_f4(tmp + ((size_t)l*BB + b)*DD, wr, DD);
}

__global__ void k_binit(unsigned* __restrict__ bar, int* __restrict__ pred){
  int tid = threadIdx.x;            // 1024 threads
  bar[tid] = 0u;
  pred[tid]        = ((tid & (TT-1)) == 0) ? 1 : 0;
  pred[tid + 1024] = (((tid + 1024) & (TT-1)) == 0) ? 1 : 0;
}

// k32-pack: in [L][N][K] row-major -> out [L][K/32][N][32]
__global__ void k_pack32(const float* __restrict__ in, float* __restrict__ out,
                         int N, int K, int total){
  int tid = blockIdx.x * blockDim.x + threadIdx.x;
  if (tid >= total) return;
  int S = N * K;
  int l = tid / S, r = tid - l*S;
  int k32 = r / (32*N);
  int r2 = r - k32*32*N;
  int n = r2 >> 5, ku = r2 & 31;
  out[tid] = in[(size_t)l*S + (size_t)n*K + k32*32 + ku];
}

// consume one cell (8 float4 = 32 k) into 2 row accumulators (rows J0, J0+1), k-ascending
#define CELL2(WARR, KOFF, J0)                                                 \
  _Pragma("unroll")                                                           \
  for (int q = 0; q < 8; ++q){                                                \
    float4 w = WARR[q];                                                       \
    const int kk = (KOFF) + q*4;                                              \
    float4 xa = *(const float4*)&sxp[(J0)*512 + kk];                          \
    float4 xb = *(const float4*)&sxp[((J0)+1)*512 + kk];                      \
    r0=fmaf(w.x,xa.x,r0); r0=fmaf(w.y,xa.y,r0); r0=fmaf(w.z,xa.z,r0); r0=fmaf(w.w,xa.w,r0); \
    r1=fmaf(w.x,xb.x,r1); r1=fmaf(w.y,xb.y,r1); r1=fmaf(w.z,xb.z,r1); r1=fmaf(w.w,xb.w,r1); \
  }

// ---------------- persistent decode kernel ----------------
struct KParams {
  const float *emb, *sab, *sob, *f1b, *f2b;
  const float *g1,*b1,*g2,*b2,*g3,*b3,*fg,*fb;
  const float *o1b,*o2b,*o3w,*o3b;
  const float *cosb,*sinb,*cac;
  const float *sawP,*sowP,*f1wP,*f2wP,*o1wP,*o2wP;   // k32-packed [K/32][N][32]
  float *kc,*vc,*xl,*qb,*at,*ao,*x2,*fo,*h1,*xf,*hh1,*hh2,*ps3;
  int *pred;
  unsigned *bar;
};

__global__ __launch_bounds__(NTHR, 4) void k_persist(KParams P){
  const int bid = blockIdx.x, tid = threadIdx.x;
  const int g = bid & 7;          // group (XCD-aligned under %8 round-robin; perf hint only)
  const int m = bid >> 3;         // member 0..63
  const int wid = tid >> 6, lane = tid & 63;
  __shared__ __align__(16) float smem[8704];

  for (int t = 1; t < TT; ++t){
    const int pp = t - 1;

    for (int l = 0; l < LL; ++l){
      // ================= S1: build x_l + QKV (48 blocks x 32 cols) =================
      {
        float* sx   = smem;          // [4][512]
        float* part = smem + 2048;   // [8][4][32]
        float* srow = smem + 4096;   // [4][2]
        const int j = tid >> 7, d4 = (tid & 127) * 4;
        const int rb = g*4 + j;
        if (l == 0){
          int tok = P.pred[rb*TT + pp];
          #pragma unroll
          for (int e = d4; e < d4 + 4; e += 2){
            int i = e >> 1;
            float c = P.cosb[pp*256 + i], s = P.sinb[pp*256 + i];
            float e0 = P.emb[(size_t)tok*DD + e];
            float e1 = P.emb[(size_t)tok*DD + e + 1];
            sx[j*512 + e]     = fmaf(e0, c, -(e1*s));
            sx[j*512 + e + 1] = fmaf(e1, c, e0*s);
          }
        } else {
          if (tid < 4){
            float a = 0.f, bq = 0.f;
            const float* pr = P.ps3 + (size_t)(g*4 + tid)*64;
            for (int s = 0; s < 32; ++s){ a += pr[s*2]; bq += pr[s*2+1]; }
            float mu = a * (1.0f/512.0f);
            float var = bq * (1.0f/512.0f) - mu*mu;
            srow[tid*2]   = mu;
            srow[tid*2+1] = 1.0f / sqrtf(var + 1e-5f);
          }
          __syncthreads();
          float mu = srow[j*2], rs = srow[j*2+1];
          float4 xv = *(const float4*)&P.x2[(size_t)rb*DD + d4];
          float4 fv = *(const float4*)&P.fo[(size_t)rb*DD + d4];
          const float* g3r = P.g3 + (size_t)(l-1)*DD;
          const float* b3r = P.b3 + (size_t)(l-1)*DD;
          float yv[4] = {xv.x+fv.x, xv.y+fv.y, xv.z+fv.z, xv.w+fv.w};
          #pragma unroll
          for (int i = 0; i < 4; ++i)
            sx[j*512 + d4 + i] = (yv[i]-mu)*rs*g3r[d4+i] + b3r[d4+i];
        }
        __syncthreads();
        if (m == 0){   // materialize x_l
          float4 v = *(float4*)&sx[j*512 + d4];
          *(float4*)&P.xl[(size_t)rb*DD + d4] = v;
        }
        if (m < 48){
          const int n0 = m*32;
          const int c = lane & 31, j0 = (lane >> 5) * 2;
          const float4* wb0 = (const float4*)P.sawP + ((size_t)l*16 + wid*2)*(1536*8)
                            + (size_t)(n0 + c)*8;
          const float4* wb1 = wb0 + 1536*8;
          float4 w0[8], w1[8];
          #pragma unroll
          for (int q = 0; q < 8; ++q) w0[q] = wb0[q];
          #pragma unroll
          for (int q = 0; q < 8; ++q) w1[q] = wb1[q];
          float r0=0.f, r1=0.f;
          const float* sxp = sx;
          const int kb = wid*64;
          CELL2(w0, kb, j0);
          CELL2(w1, kb + 32, j0);
          part[(wid*4 + j0)*32 + c]     = r0;
          part[(wid*4 + j0 + 1)*32 + c] = r1;
          __syncthreads();
          if (tid < 128){
            int jr = tid >> 5, nl = tid & 31;
            int n = n0 + nl, rb2 = g*4 + jr;
            float s = P.sab[l*1536 + n];
            #pragma unroll
            for (int w = 0; w < 8; ++w) s += part[(w*4+jr)*32 + nl];
            if (n < DD){
              P.qb[(size_t)rb2*DD + n] = s;
            } else if (n < 2*DD){
              int h = (n - DD) >> 6, hd = (n - DD) & 63;
              P.kc[((((size_t)l*BB + rb2)*HH + h)*TT + pp)*HDIM + hd] = s;
            } else {
              int h = (n - 2*DD) >> 6, hd = (n - 2*DD) & 63;
              P.vc[((((size_t)l*BB + rb2)*HH + h)*TT + pp)*HDIM + hd] = s;
            }
          }
        }
      }
      gbar(P.bar, g);

      // ================= S2: attention (32 blocks = (row,head), 1 wave) =================
      if (m < 32){
        int bl = m >> 3, h = m & 7, rb = g*4 + bl;
        float* qs = smem; float* ps = smem + 64;
        if (tid < 64) qs[tid] = P.qb[(size_t)rb*DD + h*HDIM + tid];
        __syncthreads();
        if (tid < 64){
          const float* kb = P.kc + (((size_t)l*BB + rb)*HH + h)*TT*HDIM;
          float s = -INFINITY;
          if (lane <= pp && P.pred[rb*TT + lane] != 0){
            const float* kr = kb + lane*HDIM;
            float acc = 0.f;
            #pragma unroll
            for (int k2 = 0; k2 < HDIM; ++k2) acc = fmaf(qs[k2], kr[k2], acc);
            s = acc * 0.125f;
          }
          float mx = s;
          #pragma unroll
          for (int off = 32; off; off >>= 1) mx = fmaxf(mx, __shfl_xor(mx, off));
          float e = (s == -INFINITY) ? 0.f : expf(s - mx);
          float sum = e;
          #pragma unroll
          for (int off = 32; off; off >>= 1) sum += __shfl_xor(sum, off);
          ps[lane] = e / sum;
          const float* vb = P.vc + (((size_t)l*BB + rb)*HH + h)*TT*HDIM;
          float o = 0.f;
          int jj = 0;
          for (; jj + 8 <= t; jj += 8){
            float vv[8];
            #pragma unroll
            for (int u = 0; u < 8; ++u) vv[u] = vb[(jj+u)*HDIM + lane];
            #pragma unroll
            for (int u = 0; u < 8; ++u) o = fmaf(ps[jj+u], vv[u], o);
          }
          for (; jj <= pp; ++jj) o = fmaf(ps[jj], vb[jj*HDIM + lane], o);
          P.at[(size_t)rb*DD + h*HDIM + lane] = o;
        }
      }
      gbar(P.bar, g);

      // ================= S3: oproj (64 blocks, 8 cols each) =================
      {
        float* ats  = smem;          // [4][512]
        float* part = smem + 2048;   // [8][32]
        const int j = tid >> 7, d4 = (tid & 127) * 4;
        *(float4*)&ats[j*512 + d4] = *(const float4*)&P.at[(size_t)(g*4+j)*DD + d4];
        __syncthreads();
        const int n0 = m*8;
        if (lane < 32){
          int jb = lane >> 3, nc = lane & 7;
          const float4* wb0 = (const float4*)P.sowP + ((size_t)l*16 + wid*2)*(512*8)
                            + (size_t)(n0 + nc)*8;
          const float4* wb1 = wb0 + 512*8;
          float4 w0[8], w1[8];
          #pragma unroll
          for (int q = 0; q < 8; ++q) w0[q] = wb0[q];
          #pragma unroll
          for (int q = 0; q < 8; ++q) w1[q] = wb1[q];
          float acc = 0.f;
          const int kb = wid*64;
          #pragma unroll
          for (int q = 0; q < 8; ++q){
            float4 w = w0[q];
            float4 xa = *(const float4*)&ats[jb*512 + kb + q*4];
            acc=fmaf(w.x,xa.x,acc); acc=fmaf(w.y,xa.y,acc); acc=fmaf(w.z,xa.z,acc); acc=fmaf(w.w,xa.w,acc);
          }
          #pragma unroll
          for (int q = 0; q < 8; ++q){
            float4 w = w1[q];
            float4 xa = *(const float4*)&ats[jb*512 + kb + 32 + q*4];
            acc=fmaf(w.x,xa.x,acc); acc=fmaf(w.y,xa.y,acc); acc=fmaf(w.z,xa.z,acc); acc=fmaf(w.w,xa.w,acc);
          }
          part[wid*32 + jb*8 + nc] = acc;
        }
        __syncthreads();
        if (tid < 32){
          int jb2 = tid >> 3, nc2 = tid & 7, n = n0 + nc2;
          float s = P.sob[l*DD + n];
          #pragma unroll
          for (int w = 0; w < 8; ++w) s += part[w*32 + jb2*8 + nc2];
          P.ao[(size_t)(g*4+jb2)*DD + n] = s;
        }
      }
      gbar(P.bar, g);

      // ================= S4: ln1+ln2 (redundant) + FF1 (64 blocks, 32 cols) =================
      {
        float* sx2  = smem;          // [4][512]
        float* part = smem + 2048;   // [8][4][32]
        float* wred = smem + 4096;   // [8]
        const int j = tid >> 7, d4 = (tid & 127) * 4;
        const int rb = g*4 + j;
        float4 xlv = *(const float4*)&P.xl[(size_t)rb*DD + d4];
        float4 aov = *(const float4*)&P.ao[(size_t)rb*DD + d4];
        float y[4] = {xlv.x+aov.x, xlv.y+aov.y, xlv.z+aov.z, xlv.w+aov.w};
        float s = ((y[0]+y[1])+y[2])+y[3];
        float mu = row_reduce(s, wid, j, wred) * (1.0f/512.0f);
        float dv[4], sq = 0.f;
        #pragma unroll
        for (int i = 0; i < 4; ++i){ dv[i] = y[i]-mu; sq += dv[i]*dv[i]; }
        float rs = 1.0f / sqrtf(row_reduce(sq, wid, j, wred) * (1.0f/512.0f) + 1e-5f);
        float z[4];
        #pragma unroll
        for (int i = 0; i < 4; ++i){
          int d = d4 + i;
          z[i] = dv[i]*rs*P.g1[l*DD+d] + P.b1[l*DD+d] + P.cac[((size_t)l*BB + rb)*DD + d];
        }
        float s2 = ((z[0]+z[1])+z[2])+z[3];
        float mu2 = row_reduce(s2, wid, j, wred) * (1.0f/512.0f);
        float dz[4], sq2 = 0.f;
        #pragma unroll
        for (int i = 0; i < 4; ++i){ dz[i] = z[i]-mu2; sq2 += dz[i]*dz[i]; }
        float rs2 = 1.0f / sqrtf(row_reduce(sq2, wid, j, wred) * (1.0f/512.0f) + 1e-5f);
        float x2v[4];
        #pragma unroll
        for (int i = 0; i < 4; ++i){
          int d = d4 + i;
          x2v[i] = dz[i]*rs2*P.g2[l*DD+d] + P.b2[l*DD+d];
          sx2[j*512 + d] = x2v[i];
        }
        if (m == 0) *(float4*)&P.x2[(size_t)rb*DD + d4] = make_float4(x2v[0],x2v[1],x2v[2],x2v[3]);
        __syncthreads();
        // ff1 dot: 64 blocks x 32 cols
        const int n0 = m*32;
        const int c = lane & 31, j0 = (lane >> 5) * 2;
        const float4* wb0 = (const float4*)P.f1wP + ((size_t)l*16 + wid*2)*(2048*8)
                          + (size_t)(n0 + c)*8;
        const float4* wb1 = wb0 + 2048*8;
        float4 w0[8], w1[8];
        #pragma unroll
        for (int q = 0; q < 8; ++q) w0[q] = wb0[q];
        #pragma unroll
        for (int q = 0; q < 8; ++q) w1[q] = wb1[q];
        float r0=0.f, r1=0.f;
        const float* sxp = sx2;
        const int kb = wid*64;
        CELL2(w0, kb, j0);
        CELL2(w1, kb + 32, j0);
        part[(wid*4 + j0)*32 + c]     = r0;
        part[(wid*4 + j0 + 1)*32 + c] = r1;
        __syncthreads();
        if (tid < 128){
          int jr = tid >> 5, nl = tid & 31;
          int n = n0 + nl;
          float v = P.f1b[l*FFD + n];
          #pragma unroll
          for (int w = 0; w < 8; ++w) v += part[(w*4+jr)*32 + nl];
          P.h1[(size_t)(g*4+jr)*FFD + n] = v / (1.0f + expf(-v));
        }
      }
      gbar(P.bar, g);

      // ================= S5: FF2 (32 blocks, 16 cols) + ln3 partials (exact r10) ==========
      if (m < 32){
        float* sh1  = smem;          // [4][2048]
        float* part = smem + 8192;   // [8][64]
        #pragma unroll
        for (int q = 0; q < 4; ++q){
          int fi = tid + q*512;               // float4 index over [4][512]
          int j = fi >> 9, c4 = fi & 511;
          *(float4*)&sh1[j*2048 + c4*4] = *(const float4*)&P.h1[(size_t)(g*4+j)*FFD + c4*4];
        }
        __syncthreads();
        const int n0 = m*16;
        const int jb = lane >> 4, nc = lane & 15;
        const float4* base = (const float4*)P.f2wP + ((size_t)l*64 + wid*8)*(512*8)
                           + (size_t)(n0 + nc)*8;
        float acc = 0.f;
        #pragma unroll
        for (int cc = 0; cc < 4; ++cc){
          const float4* b0 = base + (size_t)(cc*2)*(512*8);
          const float4* b1 = b0 + 512*8;
          float4 w0[8], w1[8];
          #pragma unroll
          for (int q = 0; q < 8; ++q) w0[q] = b0[q];
          #pragma unroll
          for (int q = 0; q < 8; ++q) w1[q] = b1[q];
          const int kb = wid*256 + cc*64;
          #pragma unroll
          for (int q = 0; q < 8; ++q){
            float4 w = w0[q];
            float4 xa = *(const float4*)&sh1[jb*2048 + kb + q*4];
            acc=fmaf(w.x,xa.x,acc); acc=fmaf(w.y,xa.y,acc); acc=fmaf(w.z,xa.z,acc); acc=fmaf(w.w,xa.w,acc);
          }
          #pragma unroll
          for (int q = 0; q < 8; ++q){
            float4 w = w1[q];
            float4 xa = *(const float4*)&sh1[jb*2048 + kb + 32 + q*4];
            acc=fmaf(w.x,xa.x,acc); acc=fmaf(w.y,xa.y,acc); acc=fmaf(w.z,xa.z,acc); acc=fmaf(w.w,xa.w,acc);
          }
        }
        part[wid*64 + lane] = acc;
        __syncthreads();
        if (tid < 64){
          int jb2 = tid >> 4, nc2 = tid & 15, n = n0 + nc2;
          int rb2 = g*4 + jb2;
          float val = P.f2b[l*DD + n];
          #pragma unroll
          for (int w = 0; w < 8; ++w) val += part[w*64 + jb2*16 + nc2];
          P.fo[(size_t)rb2*DD + n] = val;
          float y = P.x2[(size_t)rb2*DD + n] + val;
          float s1 = y, sq = y*y;
          #pragma unroll
          for (int off = 1; off < 16; off <<= 1){
            s1 += __shfl_xor(s1, off);
            sq += __shfl_xor(sq, off);
          }
          if (nc2 == 0){
            P.ps3[(size_t)(rb2*32 + m)*2]     = s1;
            P.ps3[(size_t)(rb2*32 + m)*2 + 1] = sq;
          }
        }
      }
      gbar(P.bar, g);
    }

    // ================= S6: final ln3 + fn ln (4 row blocks) =================
    if (m < 4){
      int rb = g*4 + m, d = tid;
      float y = P.x2[(size_t)rb*DD + d] + P.fo[(size_t)rb*DD + d];
      float xv = block_ln(y, P.g3[3*DD + d], P.b3[3*DD + d], smem);
      float o  = block_ln(xv, P.fg[d], P.fb[d], smem);
      P.xf[(size_t)rb*DD + d] = o;
    }
    gbar(P.bar, g);

    // ================= S7: head1 (64 blocks, 16 cols) =================
    {
      float* sxf  = smem;          // [4][512]
      float* part = smem + 2048;   // [8][64]
      const int j = tid >> 7, d4 = (tid & 127) * 4;
      *(float4*)&sxf[j*512 + d4] = *(const float4*)&P.xf[(size_t)(g*4+j)*DD + d4];
      __syncthreads();
      const int n0 = m*16;
      const int row = lane >> 4, col = lane & 15;
      const float4* wb0 = (const float4*)P.o1wP + (size_t)(wid*2)*(1024*8)
                        + (size_t)(n0 + col)*8;
      const float4* wb1 = wb0 + 1024*8;
      float4 w0[8], w1[8];
      #pragma unroll
      for (int q = 0; q < 8; ++q) w0[q] = wb0[q];
      #pragma unroll
      for (int q = 0; q < 8; ++q) w1[q] = wb1[q];
      float acc = 0.f;
      const int kb = wid*64;
      #pragma unroll
      for (int q = 0; q < 8; ++q){
        float4 w = w0[q];
        float4 xa = *(const float4*)&sxf[row*512 + kb + q*4];
        acc=fmaf(w.x,xa.x,acc); acc=fmaf(w.y,xa.y,acc); acc=fmaf(w.z,xa.z,acc); acc=fmaf(w.w,xa.w,acc);
      }
      #pragma unroll
      for (int q = 0; q < 8; ++q){
        float4 w = w1[q];
        float4 xa = *(const float4*)&sxf[row*512 + kb + 32 + q*4];
        acc=fmaf(w.x,xa.x,acc); acc=fmaf(w.y,xa.y,acc); acc=fmaf(w.z,xa.z,acc); acc=fmaf(w.w,xa.w,acc);
      }
      part[wid*64 + row*16 + col] = acc;
      __syncthreads();
      if (tid < 64){
        int row2 = tid >> 4, col2 = tid & 15, n = n0 + col2;
        float a = P.o1b[n];
        #pragma unroll
        for (int w = 0; w < 8; ++w) a += part[w*64 + row2*16 + col2];
        P.hh1[(size_t)(g*4+row2)*1024 + n] = 0.5f * a * (1.0f + erff(a / 1.41421356237309504880f));
      }
    }
    gbar(P.bar, g);

    // ================= S8: head2 (64 blocks, 16 cols, K=1024) =================
    {
      float* sh   = smem;          // [4][1024]
      float* part = smem + 4096;   // [8][64]
      #pragma unroll
      for (int q = 0; q < 2; ++q){
        int fi = tid + q*512;               // float4 index over [4][256]
        int j = fi >> 8, c4 = fi & 255;
        *(float4*)&sh[j*1024 + c4*4] = *(const float4*)&P.hh1[(size_t)(g*4+j)*1024 + c4*4];
      }
      __syncthreads();
      const int n0 = m*16;
      const int row = lane >> 4, col = lane & 15;
      const float4* base = (const float4*)P.o2wP + (size_t)(wid*4)*(1024*8)
                         + (size_t)(n0 + col)*8;
      float acc = 0.f;
      #pragma unroll
      for (int cc = 0; cc < 2; ++cc){
        const float4* b0 = base + (size_t)(cc*2)*(1024*8);
        const float4* b1 = b0 + 1024*8;
        float4 w0[8], w1[8];
        #pragma unroll
        for (int q = 0; q < 8; ++q) w0[q] = b0[q];
        #pragma unroll
        for (int q = 0; q < 8; ++q) w1[q] = b1[q];
        const int kb = wid*128 + cc*64;
        #pragma unroll
        for (int q = 0; q < 8; ++q){
          float4 w = w0[q];
          float4 xa = *(const float4*)&sh[row*1024 + kb + q*4];
          acc=fmaf(w.x,xa.x,acc); acc=fmaf(w.y,xa.y,acc); acc=fmaf(w.z,xa.z,acc); acc=fmaf(w.w,xa.w,acc);
        }
        #pragma unroll
        for (int q = 0; q < 8; ++q){
          float4 w = w1[q];
          float4 xa = *(const float4*)&sh[row*1024 + kb + 32 + q*4];
          acc=fmaf(w.x,xa.x,acc); acc=fmaf(w.y,xa.y,acc); acc=fmaf(w.z,xa.z,acc); acc=fmaf(w.w,xa.w,acc);
        }
      }
      part[wid*64 + row*16 + col] = acc;
      __syncthreads();
      if (tid < 64){
        int row2 = tid >> 4, col2 = tid & 15, n = n0 + col2;
        float a = P.o2b[n];
        #pragma unroll
        for (int w = 0; w < 8; ++w) a += part[w*64 + row2*16 + col2];
        P.hh2[(size_t)(g*4+row2)*1024 + n] = 0.5f * a * (1.0f + erff(a / 1.41421356237309504880f));
      }
    }
    gbar(P.bar, g);

    // ================= S9: sample (4 row blocks; exact r10 math) + embed =================
    if (m < 4){
      int rb = g*4 + m, v = tid;
      float* hrow = smem;                 // 1024
      float* red  = smem + 1024;          // 8
      int*   redi = (int*)(smem + 1032);  // 2
      int*   stok = (int*)(smem + 1040);  // 1
      for (int k = tid; k < 1024; k += NTHR) hrow[k] = P.hh2[(size_t)rb*1024 + k];
      __syncthreads();
      float sv = 0.f;
      if (tid < 128){
        float acc = P.o3b[v] + dot_f4(hrow, P.o3w + (size_t)v*1024, 1024);
        sv = acc / 0.1f;
      }
      float mx = (tid < 128) ? sv : -INFINITY;
      #pragma unroll
      for (int off = 32; off; off >>= 1) mx = fmaxf(mx, __shfl_xor(mx, off));
      __syncthreads();
      if (tid < 128 && (tid & 63) == 0) red[tid >> 6] = mx;
      __syncthreads();
      mx = fmaxf(red[0], red[1]);
      float e = (tid < 128) ? expf(sv - mx) : 0.f;
      float sum = e;
      #pragma unroll
      for (int off = 32; off; off >>= 1) sum += __shfl_xor(sum, off);
      __syncthreads();
      if (tid < 128 && (tid & 63) == 0) red[tid >> 6] = sum;
      __syncthreads();
      sum = red[0] + red[1];
      float bv = -INFINITY; int bi = 0x7fffffff;
      if (tid < 128){
        float lp = (sv - mx) - logf(sum);
        uint32_t kk0, kk1, o0, o1;
        tf2x32(0u, 1u, 0u, (uint32_t)t, &kk0, &kk1);
        tf2x32(kk0, kk1, 0u, (uint32_t)(rb*VV + v), &o0, &o1);
        uint32_t bits = o0 ^ o1;
        float u = __uint_as_float((bits >> 9) | 0x3F800000u) - 1.0f;
        float gg = -logf(-logf(u + 1e-9f) + 1e-9f);
        bv = lp + gg; bi = v;
      }
      #pragma unroll
      for (int off = 32; off; off >>= 1){
        float ov = __shfl_xor(bv, off);
        int   oi = __shfl_xor(bi, off);
        if (ov > bv || (ov == bv && oi < bi)){ bv = ov; bi = oi; }
      }
      __syncthreads();
      if (tid < 128 && (tid & 63) == 0){ red[tid >> 6] = bv; redi[tid >> 6] = bi; }
      __syncthreads();
      if (tid == 0){
        float v0 = red[0], v1 = red[1]; int i0 = redi[0], i1 = redi[1];
        int tok = (v1 > v0 || (v1 == v0 && i1 < i0)) ? i1 : i0;
        P.pred[rb*TT + t] = tok;
        *stok = tok;
      }
      __syncthreads();
      // next-step x_0 embed is recomputed in S1 (l==0) from pred; nothing else needed here
    }
    gbar(P.bar, g);
  }
}

// ---------------- host ----------------
extern "C" void kernel_launch(void* const* d_in, const int* in_sizes, int n_in,
                              void* d_out, int out_size, void* d_ws, size_t ws_size,
                              hipStream_t stream){
  (void)in_sizes; (void)n_in; (void)out_size; (void)ws_size;
  const float* mol      = (const float*)d_in[1];
  const float* sa_in_w  = (const float*)d_in[3];
  const float* sa_out_w = (const float*)d_in[5];
  const float* ca_in_w  = (const float*)d_in[7];
  const float* ca_in_b  = (const float*)d_in[8];
  const float* ca_out_w = (const float*)d_in[9];
  const float* ca_out_b = (const float*)d_in[10];
  const float* ff_w1    = (const float*)d_in[11];
  const float* ff_w2    = (const float*)d_in[13];
  const float* out_w1   = (const float*)d_in[23];
  const float* out_w2   = (const float*)d_in[25];

  KParams P;
  P.emb = (const float*)d_in[2];
  P.sab = (const float*)d_in[4];
  P.sob = (const float*)d_in[6];
  P.f1b = (const float*)d_in[12];
  P.f2b = (const float*)d_in[14];
  P.g1  = (const float*)d_in[15];
  P.b1  = (const float*)d_in[16];
  P.g2  = (const float*)d_in[17];
  P.b2  = (const float*)d_in[18];
  P.g3  = (const float*)d_in[19];
  P.b3  = (const float*)d_in[20];
  P.fg  = (const float*)d_in[21];
  P.fb  = (const float*)d_in[22];
  P.o1b = (const float*)d_in[24];
  P.o2b = (const float*)d_in[26];
  P.o3w = (const float*)d_in[27];
  P.o3b = (const float*)d_in[28];

  unsigned* bar = (unsigned*)d_ws;          // 1024 uints
  float* ws = (float*)d_ws + 1024;
  float* cosb   = ws;                       // 16384
  float* sinb   = cosb + 16384;             // 16384
  float* ca_tmp = sinb + 16384;             // 65536
  float* cac    = ca_tmp + 65536;           // 65536
  float* kc     = cac + 65536;              // 4194304
  float* vc     = kc + 4194304;             // 4194304
  float* xl     = vc + 4194304;             // 16384
  float* qb     = xl + 16384;               // 16384
  float* at     = qb + 16384;               // 16384
  float* ao     = at + 16384;               // 16384
  float* x2     = ao + 16384;               // 16384
  float* fo     = x2 + 16384;               // 16384
  float* h1     = fo + 16384;               // 65536
  float* xf     = h1 + 65536;               // 16384
  float* hh1    = xf + 16384;               // 32768
  float* hh2    = hh1 + 32768;              // 32768
  float* ps3    = hh2 + 32768;              // 2048
  float* sawP   = ps3 + 2048;               // 3145728
  float* sowP   = sawP + 3145728;           // 1048576
  float* f1wP   = sowP + 1048576;           // 4194304
  float* f2wP   = f1wP + 4194304;           // 4194304
  float* o1wP   = f2wP + 4194304;           // 524288
  float* o2wP   = o1wP + 524288;            // 1048576

  P.cosb = cosb; P.sinb = sinb; P.cac = cac;
  P.kc = kc; P.vc = vc; P.xl = xl; P.qb = qb; P.at = at; P.ao = ao;
  P.x2 = x2; P.fo = fo; P.h1 = h1; P.xf = xf; P.hh1 = hh1; P.hh2 = hh2;
  P.ps3 = ps3;
  P.sawP = sawP; P.sowP = sowP; P.f1wP = f1wP; P.f2wP = f2wP;
  P.o1wP = o1wP; P.o2wP = o2wP;
  P.pred = (int*)d_out;
  P.bar = bar;

  k_binit<<<1, 1024, 0, stream>>>(bar, P.pred);
  k_tables<<<64, 256, 0, stream>>>(cosb, sinb);
  k_ca1<<<256, 256, 0, stream>>>(mol, ca_in_w, ca_in_b, ca_tmp);
  k_ca2<<<256, 256, 0, stream>>>(ca_tmp, ca_out_w, ca_out_b, cac);

  // k32-pack all streamed weights: [L][N][K] -> [L][K/32][N][32]
  {
    int t1 = 4*1536*512;  k_pack32<<<(t1+255)/256, 256, 0, stream>>>(sa_in_w,  sawP, 1536, 512,  t1);
    int t2 = 4*512*512;   k_pack32<<<(t2+255)/256, 256, 0, stream>>>(sa_out_w, sowP,  512, 512,  t2);
    int t3 = 4*2048*512;  k_pack32<<<(t3+255)/256, 256, 0, stream>>>(ff_w1,    f1wP, 2048, 512,  t3);
    int t4 = 4*512*2048;  k_pack32<<<(t4+255)/256, 256, 0, stream>>>(ff_w2,    f2wP,  512, 2048, t4);
    int t5 = 1024*512;    k_pack32<<<(t5+255)/256, 256, 0, stream>>>(out_w1,   o1wP, 1024, 512,  t5);
    int t6 = 1024*1024;   k_pack32<<<(t6+255)/256, 256, 0, stream>>>(out_w2,   o2wP, 1024, 1024, t6);
  }

  k_persist<<<NBLK, NTHR, 0, stream>>>(P);
}

// Round 14
// 26354.779 us; speedup vs baseline: 1.5877x; 1.5877x over previous
//
#include <hip/hip_runtime.h>
#include <stdint.h>
#include <stddef.h>

#define BB 32
#define TT 64
#define DD 512
#define HH 8
#define HDIM 64
#define LL 4
#define FFD 2048
#define VV 128

#define NBLK 256
#define NTHR 512

// ---------------- threefry2x32 (20 rounds), matches JAX ----------------
__host__ __device__ inline uint32_t rotl32(uint32_t v, int n){ return (v << n) | (v >> (32 - n)); }

__host__ __device__ inline void tf2x32(uint32_t k0, uint32_t k1, uint32_t x0, uint32_t x1,
                                       uint32_t* o0, uint32_t* o1){
  uint32_t ks2 = k0 ^ k1 ^ 0x1BD11BDAu;
  x0 += k0; x1 += k1;
  x0 += x1; x1 = rotl32(x1,13); x1 ^= x0;
  x0 += x1; x1 = rotl32(x1,15); x1 ^= x0;
  x0 += x1; x1 = rotl32(x1,26); x1 ^= x0;
  x0 += x1; x1 = rotl32(x1, 6); x1 ^= x0;
  x0 += k1; x1 += ks2 + 1u;
  x0 += x1; x1 = rotl32(x1,17); x1 ^= x0;
  x0 += x1; x1 = rotl32(x1,29); x1 ^= x0;
  x0 += x1; x1 = rotl32(x1,16); x1 ^= x0;
  x0 += x1; x1 = rotl32(x1,24); x1 ^= x0;
  x0 += ks2; x1 += k0 + 2u;
  x0 += x1; x1 = rotl32(x1,13); x1 ^= x0;
  x0 += x1; x1 = rotl32(x1,15); x1 ^= x0;
  x0 += x1; x1 = rotl32(x1,26); x1 ^= x0;
  x0 += x1; x1 = rotl32(x1, 6); x1 ^= x0;
  x0 += k0; x1 += k1 + 3u;
  x0 += x1; x1 = rotl32(x1,17); x1 ^= x0;
  x0 += x1; x1 = rotl32(x1,29); x1 ^= x0;
  x0 += x1; x1 = rotl32(x1,16); x1 ^= x0;
  x0 += x1; x1 = rotl32(x1,24); x1 ^= x0;
  x0 += k1; x1 += ks2 + 4u;
  x0 += x1; x1 = rotl32(x1,13); x1 ^= x0;
  x0 += x1; x1 = rotl32(x1,15); x1 ^= x0;
  x0 += x1; x1 = rotl32(x1,26); x1 ^= x0;
  x0 += x1; x1 = rotl32(x1, 6); x1 ^= x0;
  x0 += ks2; x1 += k0 + 5u;
  *o0 = x0; *o1 = x1;
}

// ---------------- helpers ----------------
__device__ inline float dot_f4(const float* __restrict__ a, const float* __restrict__ w, int K){
  float acc = 0.f;
  const float4* a4 = (const float4*)a;
  const float4* w4 = (const float4*)w;
  int K4 = K >> 2;
  for (int k = 0; k < K4; ++k){
    float4 av = a4[k], wv = w4[k];
    acc = fmaf(av.x, wv.x, acc);
    acc = fmaf(av.y, wv.y, acc);
    acc = fmaf(av.z, wv.z, acc);
    acc = fmaf(av.w, wv.w, acc);
  }
  return acc;
}

// LayerNorm across a 512-thread block (one value per thread).
__device__ inline float block_ln(float v, float g, float bb, float* red){
  __syncthreads();
  float s = v;
  #pragma unroll
  for (int off = 32; off; off >>= 1) s += __shfl_xor(s, off);
  if ((threadIdx.x & 63) == 0) red[threadIdx.x >> 6] = s;
  __syncthreads();
  float mu = (red[0]+red[1]+red[2]+red[3]+red[4]+red[5]+red[6]+red[7]) * (1.0f/512.0f);
  float dv = v - mu;
  float sq = dv * dv;
  #pragma unroll
  for (int off = 32; off; off >>= 1) sq += __shfl_xor(sq, off);
  __syncthreads();
  if ((threadIdx.x & 63) == 0) red[threadIdx.x >> 6] = sq;
  __syncthreads();
  float var = (red[0]+red[1]+red[2]+red[3]+red[4]+red[5]+red[6]+red[7]) * (1.0f/512.0f);
  return dv * (1.0f / sqrtf(var + 1e-5f)) * g + bb;
}

// row reduction among the 128 threads (2 waves) owning row j (j = tid>>7); all 512 call.
__device__ inline float row_reduce(float v, int wid, int j, float* wred){
  #pragma unroll
  for (int off = 32; off; off >>= 1) v += __shfl_xor(v, off);
  if ((threadIdx.x & 63) == 0) wred[wid] = v;
  __syncthreads();
  float r = wred[2*j] + wred[2*j+1];
  __syncthreads();
  return r;
}

// ---------------- group barrier: 64 blocks of group g (XCD pair) ----------------
__device__ __forceinline__ void gbar(unsigned* bar, int g){
  __syncthreads();
  if (threadIdx.x == 0){
    unsigned* cnt = bar + g*64;
    unsigned* gen = bar + g*64 + 16;
    __builtin_amdgcn_fence(__ATOMIC_RELEASE, "agent");
    unsigned old = __hip_atomic_load(gen, __ATOMIC_RELAXED, __HIP_MEMORY_SCOPE_AGENT);
    if (__hip_atomic_fetch_add(cnt, 1u, __ATOMIC_RELAXED, __HIP_MEMORY_SCOPE_AGENT) == 63u){
      __hip_atomic_store(cnt, 0u, __ATOMIC_RELAXED, __HIP_MEMORY_SCOPE_AGENT);
      __hip_atomic_fetch_add(gen, 1u, __ATOMIC_RELEASE, __HIP_MEMORY_SCOPE_AGENT);
    } else {
      while (__hip_atomic_load(gen, __ATOMIC_RELAXED, __HIP_MEMORY_SCOPE_AGENT) == old)
        __builtin_amdgcn_s_sleep(1);
    }
    __builtin_amdgcn_fence(__ATOMIC_ACQUIRE, "agent");
  }
  __syncthreads();
}

// ---------------- setup kernels ----------------
__global__ void k_tables(float* __restrict__ cosb, float* __restrict__ sinb){
  int tid = blockIdx.x * blockDim.x + threadIdx.x;  // TT*256
  int p = tid >> 8, i = tid & 255;
  float sv = (2.0f * (float)i + 204.8f) / 716.8f;
  float scale = powf(sv, (float)p / 16.0f);
  float invf = 1.0f / powf(10000.0f, (float)i / 256.0f);
  float ang = (float)p * invf;
  cosb[tid] = cosf(ang) * scale;
  sinb[tid] = sinf(ang) * scale;
}

__global__ void k_ca1(const float* __restrict__ mol, const float* __restrict__ w,
                      const float* __restrict__ bias, float* __restrict__ tmp){
  int tid = blockIdx.x * blockDim.x + threadIdx.x;  // LL*BB*DD
  int l = tid >> 14; int r = tid & 16383; int b = r >> 9; int d = r & 511;
  const float* wr = w + (size_t)l*3*DD*DD + (size_t)(2*DD + d)*DD;
  tmp[tid] = bias[l*3*DD + 2*DD + d] + dot_f4(mol + (size_t)b*DD, wr, DD);
}

__global__ void k_ca2(const float* __restrict__ tmp, const float* __restrict__ w,
                      const float* __restrict__ bias, float* __restrict__ cac){
  int tid = blockIdx.x * blockDim.x + threadIdx.x;  // LL*BB*DD
  int l = tid >> 14; int r = tid & 16383; int b = r >> 9; int d = r & 511;
  const float* wr = w + (size_t)l*DD*DD + (size_t)d*DD;
  cac[tid] = bias[l*DD + d] + dot_f4(tmp + ((size_t)l*BB + b)*DD, wr, DD);
}

__global__ void k_binit(unsigned* __restrict__ bar, int* __restrict__ pred){
  int tid = threadIdx.x;            // 1024 threads
  bar[tid] = 0u;
  pred[tid]        = ((tid & (TT-1)) == 0) ? 1 : 0;
  pred[tid + 1024] = (((tid + 1024) & (TT-1)) == 0) ? 1 : 0;
}

// k32-pack: in [L][N][K] row-major -> out [L][K/32][N][32]
__global__ void k_pack32(const float* __restrict__ in, float* __restrict__ out,
                         int N, int K, int total){
  int tid = blockIdx.x * blockDim.x + threadIdx.x;
  if (tid >= total) return;
  int S = N * K;
  int l = tid / S, r = tid - l*S;
  int k32 = r / (32*N);
  int r2 = r - k32*32*N;
  int n = r2 >> 5, ku = r2 & 31;
  out[tid] = in[(size_t)l*S + (size_t)n*K + k32*32 + ku];
}

// consume one cell (8 float4 = 32 k) into 8 row accumulators, k-ascending per row
#define CELL8(WARR, KOFF)                                                     \
  _Pragma("unroll")                                                           \
  for (int q = 0; q < 8; ++q){                                                \
    float4 w = WARR[q];                                                       \
    const int kk = (KOFF) + q*4;                                              \
    _Pragma("unroll")                                                         \
    for (int r_ = 0; r_ < 8; ++r_){                                           \
      float4 x = *(const float4*)&sxp[r_*512 + kk];                           \
      a[r_]=fmaf(w.x,x.x,a[r_]); a[r_]=fmaf(w.y,x.y,a[r_]);                   \
      a[r_]=fmaf(w.z,x.z,a[r_]); a[r_]=fmaf(w.w,x.w,a[r_]);                   \
    }                                                                         \
  }

// ---------------- persistent decode kernel ----------------
struct KParams {
  const float *emb, *sab, *sob, *f1b, *f2b;
  const float *g1,*b1,*g2,*b2,*g3,*b3,*fg,*fb;
  const float *o1b,*o2b,*o3w,*o3b;
  const float *cosb,*sinb,*cac;
  const float *sawP,*sowP,*f1wP,*f2wP,*o1wP,*o2wP;   // k32-packed [K/32][N][32]
  float *kc,*vc,*xl,*qb,*at,*ao,*x2,*fo,*h1,*xf,*hh1,*hh2,*ps3;
  int *pred;
  unsigned *bar;
};

__global__ __launch_bounds__(NTHR) void k_persist(KParams P){
  const int bid = blockIdx.x, tid = threadIdx.x;
  const int g = bid & 3;          // group spans XCDs {g, g+4} under %8 round-robin
  const int m = bid >> 2;         // member 0..63
  const int wid = tid >> 6, lane = tid & 63;
  __shared__ __align__(16) float smem[17472];   // ~70 KB

  for (int t = 1; t < TT; ++t){
    const int pp = t - 1;

    for (int l = 0; l < LL; ++l){
      // ================= S1: build x_l (8 rows) + QKV (24 blocks x 64 cols x 8 rows) ======
      if (m < 24){
        float* sx   = smem;          // [8][512]
        float* part = smem + 4096;   // [8][8][64]
        float* srow = smem + 8192;   // [8][2]
        if (l == 0){
          #pragma unroll
          for (int it = 0; it < 2; ++it){
            int j = it*4 + (tid >> 7), d4 = (tid & 127) * 4;
            int rb = g*8 + j;
            int tok = P.pred[rb*TT + pp];
            #pragma unroll
            for (int e = d4; e < d4 + 4; e += 2){
              int i = e >> 1;
              float c = P.cosb[pp*256 + i], s = P.sinb[pp*256 + i];
              float e0 = P.emb[(size_t)tok*DD + e];
              float e1 = P.emb[(size_t)tok*DD + e + 1];
              sx[j*512 + e]     = fmaf(e0, c, -(e1*s));
              sx[j*512 + e + 1] = fmaf(e1, c, e0*s);
            }
          }
        } else {
          if (tid < 8){
            float aa = 0.f, bq = 0.f;
            const float* pr = P.ps3 + (size_t)(g*8 + tid)*64;
            for (int s = 0; s < 32; ++s){ aa += pr[s*2]; bq += pr[s*2+1]; }
            float mu = aa * (1.0f/512.0f);
            float var = bq * (1.0f/512.0f) - mu*mu;
            srow[tid*2]   = mu;
            srow[tid*2+1] = 1.0f / sqrtf(var + 1e-5f);
          }
          __syncthreads();
          #pragma unroll
          for (int it = 0; it < 2; ++it){
            int j = it*4 + (tid >> 7), d4 = (tid & 127) * 4;
            int rb = g*8 + j;
            float mu = srow[j*2], rs = srow[j*2+1];
            float4 xv = *(const float4*)&P.x2[(size_t)rb*DD + d4];
            float4 fv = *(const float4*)&P.fo[(size_t)rb*DD + d4];
            const float* g3r = P.g3 + (size_t)(l-1)*DD;
            const float* b3r = P.b3 + (size_t)(l-1)*DD;
            float yv[4] = {xv.x+fv.x, xv.y+fv.y, xv.z+fv.z, xv.w+fv.w};
            #pragma unroll
            for (int i = 0; i < 4; ++i)
              sx[j*512 + d4 + i] = (yv[i]-mu)*rs*g3r[d4+i] + b3r[d4+i];
          }
        }
        __syncthreads();
        if (m == 0){   // materialize x_l (all 8 rows)
          #pragma unroll
          for (int it = 0; it < 2; ++it){
            int j = it*4 + (tid >> 7), d4 = (tid & 127) * 4;
            *(float4*)&P.xl[(size_t)(g*8+j)*DD + d4] = *(float4*)&sx[j*512 + d4];
          }
        }
        // qkv dot
        const int n0 = m*64;
        const float4* wb0 = (const float4*)P.sawP + ((size_t)l*16 + wid*2)*(1536*8)
                          + (size_t)(n0 + lane)*8;
        const float4* wb1 = wb0 + 1536*8;
        float4 w0[8], w1[8];
        #pragma unroll
        for (int q = 0; q < 8; ++q) w0[q] = wb0[q];
        #pragma unroll
        for (int q = 0; q < 8; ++q) w1[q] = wb1[q];
        float a[8] = {0.f,0.f,0.f,0.f,0.f,0.f,0.f,0.f};
        const float* sxp = sx;
        const int kb = wid*64;
        CELL8(w0, kb);
        CELL8(w1, kb + 32);
        #pragma unroll
        for (int r_ = 0; r_ < 8; ++r_) part[(wid*8 + r_)*64 + lane] = a[r_];
        __syncthreads();
        {
          int jr = tid >> 6, nl = tid & 63;
          int n = n0 + nl, rb2 = g*8 + jr;
          float s = P.sab[l*1536 + n];
          #pragma unroll
          for (int w = 0; w < 8; ++w) s += part[(w*8+jr)*64 + nl];
          if (n < DD){
            P.qb[(size_t)rb2*DD + n] = s;
          } else if (n < 2*DD){
            int h = (n - DD) >> 6, hd = (n - DD) & 63;
            P.kc[((((size_t)l*BB + rb2)*HH + h)*TT + pp)*HDIM + hd] = s;
          } else {
            int h = (n - 2*DD) >> 6, hd = (n - 2*DD) & 63;
            P.vc[((((size_t)l*BB + rb2)*HH + h)*TT + pp)*HDIM + hd] = s;
          }
        }
      }
      gbar(P.bar, g);

      // ================= S2: attention (64 blocks = 8 rows x 8 heads, 1 wave) ============
      {
        int bl = m >> 3, h = m & 7, rb = g*8 + bl;
        float* qs = smem; float* ps = smem + 64;
        if (tid < 64) qs[tid] = P.qb[(size_t)rb*DD + h*HDIM + tid];
        __syncthreads();
        if (tid < 64){
          const float* kb = P.kc + (((size_t)l*BB + rb)*HH + h)*TT*HDIM;
          float s = -INFINITY;
          if (lane <= pp && P.pred[rb*TT + lane] != 0){
            const float* kr = kb + lane*HDIM;
            float acc = 0.f;
            #pragma unroll
            for (int k2 = 0; k2 < HDIM; ++k2) acc = fmaf(qs[k2], kr[k2], acc);
            s = acc * 0.125f;
          }
          float mx = s;
          #pragma unroll
          for (int off = 32; off; off >>= 1) mx = fmaxf(mx, __shfl_xor(mx, off));
          float e = (s == -INFINITY) ? 0.f : expf(s - mx);
          float sum = e;
          #pragma unroll
          for (int off = 32; off; off >>= 1) sum += __shfl_xor(sum, off);
          ps[lane] = e / sum;
          const float* vb = P.vc + (((size_t)l*BB + rb)*HH + h)*TT*HDIM;
          float o = 0.f;
          int jj = 0;
          for (; jj + 8 <= t; jj += 8){
            float vv[8];
            #pragma unroll
            for (int u = 0; u < 8; ++u) vv[u] = vb[(jj+u)*HDIM + lane];
            #pragma unroll
            for (int u = 0; u < 8; ++u) o = fmaf(ps[jj+u], vv[u], o);
          }
          for (; jj <= pp; ++jj) o = fmaf(ps[jj], vb[jj*HDIM + lane], o);
          P.at[(size_t)rb*DD + h*HDIM + lane] = o;
        }
      }
      gbar(P.bar, g);

      // ================= S3: oproj (32 blocks x 16 cols x 8 rows) =================
      if (m < 32){
        float* ats  = smem;          // [8][512]
        float* part = smem + 4096;   // [8][128]
        #pragma unroll
        for (int q = 0; q < 2; ++q){
          int fi = tid + q*512;               // float4 index over [8][128]
          int j = fi >> 7, c4 = fi & 127;
          *(float4*)&ats[j*512 + c4*4] = *(const float4*)&P.at[(size_t)(g*8+j)*DD + c4*4];
        }
        __syncthreads();
        const int n0 = m*16;
        const int jb = lane >> 4, nc = lane & 15;
        const float4* wb0 = (const float4*)P.sowP + ((size_t)l*16 + wid*2)*(512*8)
                          + (size_t)(n0 + nc)*8;
        const float4* wb1 = wb0 + 512*8;
        float4 w0[8], w1[8];
        #pragma unroll
        for (int q = 0; q < 8; ++q) w0[q] = wb0[q];
        #pragma unroll
        for (int q = 0; q < 8; ++q) w1[q] = wb1[q];
        float ac0 = 0.f, ac1 = 0.f;     // rows jb and jb+4
        const int kb = wid*64;
        #pragma unroll
        for (int q = 0; q < 8; ++q){
          float4 w = w0[q];
          float4 xa = *(const float4*)&ats[jb*512 + kb + q*4];
          float4 xb = *(const float4*)&ats[(jb+4)*512 + kb + q*4];
          ac0=fmaf(w.x,xa.x,ac0); ac0=fmaf(w.y,xa.y,ac0); ac0=fmaf(w.z,xa.z,ac0); ac0=fmaf(w.w,xa.w,ac0);
          ac1=fmaf(w.x,xb.x,ac1); ac1=fmaf(w.y,xb.y,ac1); ac1=fmaf(w.z,xb.z,ac1); ac1=fmaf(w.w,xb.w,ac1);
        }
        #pragma unroll
        for (int q = 0; q < 8; ++q){
          float4 w = w1[q];
          float4 xa = *(const float4*)&ats[jb*512 + kb + 32 + q*4];
          float4 xb = *(const float4*)&ats[(jb+4)*512 + kb + 32 + q*4];
          ac0=fmaf(w.x,xa.x,ac0); ac0=fmaf(w.y,xa.y,ac0); ac0=fmaf(w.z,xa.z,ac0); ac0=fmaf(w.w,xa.w,ac0);
          ac1=fmaf(w.x,xb.x,ac1); ac1=fmaf(w.y,xb.y,ac1); ac1=fmaf(w.z,xb.z,ac1); ac1=fmaf(w.w,xb.w,ac1);
        }
        part[wid*128 + jb*16 + nc]       = ac0;
        part[wid*128 + (jb+4)*16 + nc]   = ac1;
        __syncthreads();
        if (tid < 128){
          int jb2 = tid >> 4, nc2 = tid & 15, n = n0 + nc2;
          float s = P.sob[l*DD + n];
          #pragma unroll
          for (int w = 0; w < 8; ++w) s += part[w*128 + jb2*16 + nc2];
          P.ao[(size_t)(g*8+jb2)*DD + n] = s;
        }
      }
      gbar(P.bar, g);

      // ================= S4: ln1+ln2 (redundant, 2 passes) + FF1 (32 blocks x 64 cols x 8 rows)
      if (m < 32){
        float* sx2  = smem;          // [8][512]
        float* part = smem + 4096;   // [8][8][64]
        float* wred = smem + 8192;   // [8]
        #pragma unroll
        for (int it = 0; it < 2; ++it){
          int j = tid >> 7, d4 = (tid & 127) * 4;
          int jr = it*4 + j;
          int rb = g*8 + jr;
          float4 xlv = *(const float4*)&P.xl[(size_t)rb*DD + d4];
          float4 aov = *(const float4*)&P.ao[(size_t)rb*DD + d4];
          float y[4] = {xlv.x+aov.x, xlv.y+aov.y, xlv.z+aov.z, xlv.w+aov.w};
          float s = ((y[0]+y[1])+y[2])+y[3];
          float mu = row_reduce(s, wid, j, wred) * (1.0f/512.0f);
          float dv[4], sq = 0.f;
          #pragma unroll
          for (int i = 0; i < 4; ++i){ dv[i] = y[i]-mu; sq += dv[i]*dv[i]; }
          float rs = 1.0f / sqrtf(row_reduce(sq, wid, j, wred) * (1.0f/512.0f) + 1e-5f);
          float z[4];
          #pragma unroll
          for (int i = 0; i < 4; ++i){
            int d = d4 + i;
            z[i] = dv[i]*rs*P.g1[l*DD+d] + P.b1[l*DD+d] + P.cac[((size_t)l*BB + rb)*DD + d];
          }
          float s2 = ((z[0]+z[1])+z[2])+z[3];
          float mu2 = row_reduce(s2, wid, j, wred) * (1.0f/512.0f);
          float dz[4], sq2 = 0.f;
          #pragma unroll
          for (int i = 0; i < 4; ++i){ dz[i] = z[i]-mu2; sq2 += dz[i]*dz[i]; }
          float rs2 = 1.0f / sqrtf(row_reduce(sq2, wid, j, wred) * (1.0f/512.0f) + 1e-5f);
          #pragma unroll
          for (int i = 0; i < 4; ++i){
            int d = d4 + i;
            float x2v = dz[i]*rs2*P.g2[l*DD+d] + P.b2[l*DD+d];
            sx2[jr*512 + d] = x2v;
          }
        }
        __syncthreads();
        if (m == 0){
          #pragma unroll
          for (int it = 0; it < 2; ++it){
            int jr = it*4 + (tid >> 7), d4 = (tid & 127) * 4;
            *(float4*)&P.x2[(size_t)(g*8+jr)*DD + d4] = *(float4*)&sx2[jr*512 + d4];
          }
        }
        // ff1 dot
        const int n0 = m*64;
        const float4* wb0 = (const float4*)P.f1wP + ((size_t)l*16 + wid*2)*(2048*8)
                          + (size_t)(n0 + lane)*8;
        const float4* wb1 = wb0 + 2048*8;
        float4 w0[8], w1[8];
        #pragma unroll
        for (int q = 0; q < 8; ++q) w0[q] = wb0[q];
        #pragma unroll
        for (int q = 0; q < 8; ++q) w1[q] = wb1[q];
        float a[8] = {0.f,0.f,0.f,0.f,0.f,0.f,0.f,0.f};
        const float* sxp = sx2;
        const int kb = wid*64;
        CELL8(w0, kb);
        CELL8(w1, kb + 32);
        #pragma unroll
        for (int r_ = 0; r_ < 8; ++r_) part[(wid*8 + r_)*64 + lane] = a[r_];
        __syncthreads();
        {
          int jr = tid >> 6, nl = tid & 63;
          int n = n0 + nl;
          float v = P.f1b[l*FFD + n];
          #pragma unroll
          for (int w = 0; w < 8; ++w) v += part[(w*8+jr)*64 + nl];
          P.h1[(size_t)(g*8+jr)*FFD + n] = v / (1.0f + expf(-v));
        }
      }
      gbar(P.bar, g);

      // ================= S5: FF2 (32 blocks x 16 cols x 8 rows) + ln3 partials ===========
      if (m < 32){
        float* sh1  = smem;          // [8][2048] = 64 KB
        float* part = smem + 16384;  // [8][128]
        #pragma unroll
        for (int q = 0; q < 8; ++q){
          int fi = tid + q*512;               // float4 index over [8][512]
          int j = fi >> 9, c4 = fi & 511;
          *(float4*)&sh1[j*2048 + c4*4] = *(const float4*)&P.h1[(size_t)(g*8+j)*FFD + c4*4];
        }
        __syncthreads();
        const int n0 = m*16;
        const int jb = lane >> 4, nc = lane & 15;
        const float4* base = (const float4*)P.f2wP + ((size_t)l*64 + wid*8)*(512*8)
                           + (size_t)(n0 + nc)*8;
        float ac0 = 0.f, ac1 = 0.f;    // rows jb, jb+4
        #pragma unroll
        for (int cc = 0; cc < 4; ++cc){
          const float4* b0 = base + (size_t)(cc*2)*(512*8);
          const float4* b1 = b0 + 512*8;
          float4 w0[8], w1[8];
          #pragma unroll
          for (int q = 0; q < 8; ++q) w0[q] = b0[q];
          #pragma unroll
          for (int q = 0; q < 8; ++q) w1[q] = b1[q];
          const int kb = wid*256 + cc*64;
          #pragma unroll
          for (int q = 0; q < 8; ++q){
            float4 w = w0[q];
            float4 xa = *(const float4*)&sh1[jb*2048 + kb + q*4];
            float4 xb = *(const float4*)&sh1[(jb+4)*2048 + kb + q*4];
            ac0=fmaf(w.x,xa.x,ac0); ac0=fmaf(w.y,xa.y,ac0); ac0=fmaf(w.z,xa.z,ac0); ac0=fmaf(w.w,xa.w,ac0);
            ac1=fmaf(w.x,xb.x,ac1); ac1=fmaf(w.y,xb.y,ac1); ac1=fmaf(w.z,xb.z,ac1); ac1=fmaf(w.w,xb.w,ac1);
          }
          #pragma unroll
          for (int q = 0; q < 8; ++q){
            float4 w = w1[q];
            float4 xa = *(const float4*)&sh1[jb*2048 + kb + 32 + q*4];
            float4 xb = *(const float4*)&sh1[(jb+4)*2048 + kb + 32 + q*4];
            ac0=fmaf(w.x,xa.x,ac0); ac0=fmaf(w.y,xa.y,ac0); ac0=fmaf(w.z,xa.z,ac0); ac0=fmaf(w.w,xa.w,ac0);
            ac1=fmaf(w.x,xb.x,ac1); ac1=fmaf(w.y,xb.y,ac1); ac1=fmaf(w.z,xb.z,ac1); ac1=fmaf(w.w,xb.w,ac1);
          }
        }
        part[wid*128 + jb*16 + nc]     = ac0;
        part[wid*128 + (jb+4)*16 + nc] = ac1;
        __syncthreads();
        if (tid < 128){
          int jb2 = tid >> 4, nc2 = tid & 15, n = n0 + nc2;
          int rb2 = g*8 + jb2;
          float val = P.f2b[l*DD + n];
          #pragma unroll
          for (int w = 0; w < 8; ++w) val += part[w*128 + jb2*16 + nc2];
          P.fo[(size_t)rb2*DD + n] = val;
          float y = P.x2[(size_t)rb2*DD + n] + val;
          float s1 = y, sq = y*y;
          #pragma unroll
          for (int off = 1; off < 16; off <<= 1){
            s1 += __shfl_xor(s1, off);
            sq += __shfl_xor(sq, off);
          }
          if (nc2 == 0){
            P.ps3[(size_t)(rb2*32 + m)*2]     = s1;
            P.ps3[(size_t)(rb2*32 + m)*2 + 1] = sq;
          }
        }
      }
      gbar(P.bar, g);
    }

    // ================= S6: final ln3 + fn ln (8 row blocks) =================
    if (m < 8){
      int rb = g*8 + m, d = tid;
      float y = P.x2[(size_t)rb*DD + d] + P.fo[(size_t)rb*DD + d];
      float xv = block_ln(y, P.g3[3*DD + d], P.b3[3*DD + d], smem);
      float o  = block_ln(xv, P.fg[d], P.fb[d], smem);
      P.xf[(size_t)rb*DD + d] = o;
    }
    gbar(P.bar, g);

    // ================= S7: head1 (32 blocks x 32 cols x 8 rows) =================
    if (m < 32){
      float* sxf  = smem;          // [8][512]
      float* part = smem + 4096;   // [8][8][32]
      #pragma unroll
      for (int q = 0; q < 2; ++q){
        int fi = tid + q*512;
        int j = fi >> 7, c4 = fi & 127;
        *(float4*)&sxf[j*512 + c4*4] = *(const float4*)&P.xf[(size_t)(g*8+j)*DD + c4*4];
      }
      __syncthreads();
      const int n0 = m*32;
      const int jh = lane >> 5, nc = lane & 31;
      const float4* wb0 = (const float4*)P.o1wP + (size_t)(wid*2)*(1024*8)
                        + (size_t)(n0 + nc)*8;
      const float4* wb1 = wb0 + 1024*8;
      float4 w0[8], w1[8];
      #pragma unroll
      for (int q = 0; q < 8; ++q) w0[q] = wb0[q];
      #pragma unroll
      for (int q = 0; q < 8; ++q) w1[q] = wb1[q];
      float ac[4] = {0.f,0.f,0.f,0.f};    // rows jh + 2*ai
      const int kb = wid*64;
      #pragma unroll
      for (int q = 0; q < 8; ++q){
        float4 w = w0[q];
        #pragma unroll
        for (int ai = 0; ai < 4; ++ai){
          float4 x = *(const float4*)&sxf[(jh+2*ai)*512 + kb + q*4];
          ac[ai]=fmaf(w.x,x.x,ac[ai]); ac[ai]=fmaf(w.y,x.y,ac[ai]);
          ac[ai]=fmaf(w.z,x.z,ac[ai]); ac[ai]=fmaf(w.w,x.w,ac[ai]);
        }
      }
      #pragma unroll
      for (int q = 0; q < 8; ++q){
        float4 w = w1[q];
        #pragma unroll
        for (int ai = 0; ai < 4; ++ai){
          float4 x = *(const float4*)&sxf[(jh+2*ai)*512 + kb + 32 + q*4];
          ac[ai]=fmaf(w.x,x.x,ac[ai]); ac[ai]=fmaf(w.y,x.y,ac[ai]);
          ac[ai]=fmaf(w.z,x.z,ac[ai]); ac[ai]=fmaf(w.w,x.w,ac[ai]);
        }
      }
      #pragma unroll
      for (int ai = 0; ai < 4; ++ai) part[(wid*8 + (jh+2*ai))*32 + nc] = ac[ai];
      __syncthreads();
      if (tid < 256){
        int row = tid >> 5, nc2 = tid & 31, n = n0 + nc2;
        float aa = P.o1b[n];
        #pragma unroll
        for (int w = 0; w < 8; ++w) aa += part[(w*8+row)*32 + nc2];
        P.hh1[(size_t)(g*8+row)*1024 + n] = 0.5f * aa * (1.0f + erff(aa / 1.41421356237309504880f));
      }
    }
    gbar(P.bar, g);

    // ================= S8: head2 (32 blocks x 32 cols x 8 rows, K=1024) =================
    if (m < 32){
      float* sh   = smem;          // [8][1024]
      float* part = smem + 8192;   // [8][8][32]
      #pragma unroll
      for (int q = 0; q < 4; ++q){
        int fi = tid + q*512;
        int j = fi >> 8, c4 = fi & 255;
        *(float4*)&sh[j*1024 + c4*4] = *(const float4*)&P.hh1[(size_t)(g*8+j)*1024 + c4*4];
      }
      __syncthreads();
      const int n0 = m*32;
      const int jh = lane >> 5, nc = lane & 31;
      const float4* base = (const float4*)P.o2wP + (size_t)(wid*4)*(1024*8)
                         + (size_t)(n0 + nc)*8;
      float ac[4] = {0.f,0.f,0.f,0.f};
      #pragma unroll
      for (int cc = 0; cc < 2; ++cc){
        const float4* b0 = base + (size_t)(cc*2)*(1024*8);
        const float4* b1 = b0 + 1024*8;
        float4 w0[8], w1[8];
        #pragma unroll
        for (int q = 0; q < 8; ++q) w0[q] = b0[q];
        #pragma unroll
        for (int q = 0; q < 8; ++q) w1[q] = b1[q];
        const int kb = wid*128 + cc*64;
        #pragma unroll
        for (int q = 0; q < 8; ++q){
          float4 w = w0[q];
          #pragma unroll
          for (int ai = 0; ai < 4; ++ai){
            float4 x = *(const float4*)&sh[(jh+2*ai)*1024 + kb + q*4];
            ac[ai]=fmaf(w.x,x.x,ac[ai]); ac[ai]=fmaf(w.y,x.y,ac[ai]);
            ac[ai]=fmaf(w.z,x.z,ac[ai]); ac[ai]=fmaf(w.w,x.w,ac[ai]);
          }
        }
        #pragma unroll
        for (int q = 0; q < 8; ++q){
          float4 w = w1[q];
          #pragma unroll
          for (int ai = 0; ai < 4; ++ai){
            float4 x = *(const float4*)&sh[(jh+2*ai)*1024 + kb + 32 + q*4];
            ac[ai]=fmaf(w.x,x.x,ac[ai]); ac[ai]=fmaf(w.y,x.y,ac[ai]);
            ac[ai]=fmaf(w.z,x.z,ac[ai]); ac[ai]=fmaf(w.w,x.w,ac[ai]);
          }
        }
      }
      #pragma unroll
      for (int ai = 0; ai < 4; ++ai) part[(wid*8 + (jh+2*ai))*32 + nc] = ac[ai];
      __syncthreads();
      if (tid < 256){
        int row = tid >> 5, nc2 = tid & 31, n = n0 + nc2;
        float aa = P.o2b[n];
        #pragma unroll
        for (int w = 0; w < 8; ++w) aa += part[(w*8+row)*32 + nc2];
        P.hh2[(size_t)(g*8+row)*1024 + n] = 0.5f * aa * (1.0f + erff(aa / 1.41421356237309504880f));
      }
    }
    gbar(P.bar, g);

    // ================= S9: sample (8 row blocks; exact r10 math) =================
    if (m < 8){
      int rb = g*8 + m, v = tid;
      float* hrow = smem;                 // 1024
      float* red  = smem + 1024;          // 8
      int*   redi = (int*)(smem + 1032);  // 2
      for (int k = tid; k < 1024; k += NTHR) hrow[k] = P.hh2[(size_t)rb*1024 + k];
      __syncthreads();
      float sv = 0.f;
      if (tid < 128){
        float acc = P.o3b[v] + dot_f4(hrow, P.o3w + (size_t)v*1024, 1024);
        sv = acc / 0.1f;
      }
      float mx = (tid < 128) ? sv : -INFINITY;
      #pragma unroll
      for (int off = 32; off; off >>= 1) mx = fmaxf(mx, __shfl_xor(mx, off));
      __syncthreads();
      if (tid < 128 && (tid & 63) == 0) red[tid >> 6] = mx;
      __syncthreads();
      mx = fmaxf(red[0], red[1]);
      float e = (tid < 128) ? expf(sv - mx) : 0.f;
      float sum = e;
      #pragma unroll
      for (int off = 32; off; off >>= 1) sum += __shfl_xor(sum, off);
      __syncthreads();
      if (tid < 128 && (tid & 63) == 0) red[tid >> 6] = sum;
      __syncthreads();
      sum = red[0] + red[1];
      float bv = -INFINITY; int bi = 0x7fffffff;
      if (tid < 128){
        float lp = (sv - mx) - logf(sum);
        uint32_t kk0, kk1, o0, o1;
        tf2x32(0u, 1u, 0u, (uint32_t)t, &kk0, &kk1);
        tf2x32(kk0, kk1, 0u, (uint32_t)(rb*VV + v), &o0, &o1);
        uint32_t bits = o0 ^ o1;
        float u = __uint_as_float((bits >> 9) | 0x3F800000u) - 1.0f;
        float gg = -logf(-logf(u + 1e-9f) + 1e-9f);
        bv = lp + gg; bi = v;
      }
      #pragma unroll
      for (int off = 32; off; off >>= 1){
        float ov = __shfl_xor(bv, off);
        int   oi = __shfl_xor(bi, off);
        if (ov > bv || (ov == bv && oi < bi)){ bv = ov; bi = oi; }
      }
      __syncthreads();
      if (tid < 128 && (tid & 63) == 0){ red[tid >> 6] = bv; redi[tid >> 6] = bi; }
      __syncthreads();
      if (tid == 0){
        float v0 = red[0], v1 = red[1]; int i0 = redi[0], i1 = redi[1];
        P.pred[rb*TT + t] = (v1 > v0 || (v1 == v0 && i1 < i0)) ? i1 : i0;
      }
    }
    gbar(P.bar, g);
  }
}

// ---------------- host ----------------
extern "C" void kernel_launch(void* const* d_in, const int* in_sizes, int n_in,
                              void* d_out, int out_size, void* d_ws, size_t ws_size,
                              hipStream_t stream){
  (void)in_sizes; (void)n_in; (void)out_size; (void)ws_size;
  const float* mol      = (const float*)d_in[1];
  const float* sa_in_w  = (const float*)d_in[3];
  const float* sa_out_w = (const float*)d_in[5];
  const float* ca_in_w  = (const float*)d_in[7];
  const float* ca_in_b  = (const float*)d_in[8];
  const float* ca_out_w = (const float*)d_in[9];
  const float* ca_out_b = (const float*)d_in[10];
  const float* ff_w1    = (const float*)d_in[11];
  const float* ff_w2    = (const float*)d_in[13];
  const float* out_w1   = (const float*)d_in[23];
  const float* out_w2   = (const float*)d_in[25];

  KParams P;
  P.emb = (const float*)d_in[2];
  P.sab = (const float*)d_in[4];
  P.sob = (const float*)d_in[6];
  P.f1b = (const float*)d_in[12];
  P.f2b = (const float*)d_in[14];
  P.g1  = (const float*)d_in[15];
  P.b1  = (const float*)d_in[16];
  P.g2  = (const float*)d_in[17];
  P.b2  = (const float*)d_in[18];
  P.g3  = (const float*)d_in[19];
  P.b3  = (const float*)d_in[20];
  P.fg  = (const float*)d_in[21];
  P.fb  = (const float*)d_in[22];
  P.o1b = (const float*)d_in[24];
  P.o2b = (const float*)d_in[26];
  P.o3w = (const float*)d_in[27];
  P.o3b = (const float*)d_in[28];

  unsigned* bar = (unsigned*)d_ws;          // 1024 uints
  float* ws = (float*)d_ws + 1024;
  float* cosb   = ws;                       // 16384
  float* sinb   = cosb + 16384;             // 16384
  float* ca_tmp = sinb + 16384;             // 65536
  float* cac    = ca_tmp + 65536;           // 65536
  float* kc     = cac + 65536;              // 4194304
  float* vc     = kc + 4194304;             // 4194304
  float* xl     = vc + 4194304;             // 16384
  float* qb     = xl + 16384;               // 16384
  float* at     = qb + 16384;               // 16384
  float* ao     = at + 16384;               // 16384
  float* x2     = ao + 16384;               // 16384
  float* fo     = x2 + 16384;               // 16384
  float* h1     = fo + 16384;               // 65536
  float* xf     = h1 + 65536;               // 16384
  float* hh1    = xf + 16384;               // 32768
  float* hh2    = hh1 + 32768;              // 32768
  float* ps3    = hh2 + 32768;              // 2048
  float* sawP   = ps3 + 2048;               // 3145728
  float* sowP   = sawP + 3145728;           // 1048576
  float* f1wP   = sowP + 1048576;           // 4194304
  float* f2wP   = f1wP + 4194304;           // 4194304
  float* o1wP   = f2wP + 4194304;           // 524288
  float* o2wP   = o1wP + 524288;            // 1048576

  P.cosb = cosb; P.sinb = sinb; P.cac = cac;
  P.kc = kc; P.vc = vc; P.xl = xl; P.qb = qb; P.at = at; P.ao = ao;
  P.x2 = x2; P.fo = fo; P.h1 = h1; P.xf = xf; P.hh1 = hh1; P.hh2 = hh2;
  P.ps3 = ps3;
  P.sawP = sawP; P.sowP = sowP; P.f1wP = f1wP; P.f2wP = f2wP;
  P.o1wP = o1wP; P.o2wP = o2wP;
  P.pred = (int*)d_out;
  P.bar = bar;

  k_binit<<<1, 1024, 0, stream>>>(bar, P.pred);
  k_tables<<<64, 256, 0, stream>>>(cosb, sinb);
  k_ca1<<<256, 256, 0, stream>>>(mol, ca_in_w, ca_in_b, ca_tmp);
  k_ca2<<<256, 256, 0, stream>>>(ca_tmp, ca_out_w, ca_out_b, cac);

  // k32-pack all streamed weights: [L][N][K] -> [L][K/32][N][32]
  {
    int t1 = 4*1536*512;  k_pack32<<<(t1+255)/256, 256, 0, stream>>>(sa_in_w,  sawP, 1536, 512,  t1);
    int t2 = 4*512*512;   k_pack32<<<(t2+255)/256, 256, 0, stream>>>(sa_out_w, sowP,  512, 512,  t2);
    int t3 = 4*2048*512;  k_pack32<<<(t3+255)/256, 256, 0, stream>>>(ff_w1,    f1wP, 2048, 512,  t3);
    int t4 = 4*512*2048;  k_pack32<<<(t4+255)/256, 256, 0, stream>>>(ff_w2,    f2wP,  512, 2048, t4);
    int t5 = 1024*512;    k_pack32<<<(t5+255)/256, 256, 0, stream>>>(out_w1,   o1wP, 1024, 512,  t5);
    int t6 = 1024*1024;   k_pack32<<<(t6+255)/256, 256, 0, stream>>>(out_w2,   o2wP, 1024, 1024, t6);
  }

  k_persist<<<NBLK, NTHR, 0, stream>>>(P);
}

// Round 15
// 24767.764 us; speedup vs baseline: 1.6894x; 1.0641x over previous
//
#include <hip/hip_runtime.h>
#include <stdint.h>
#include <stddef.h>

#define BB 32
#define TT 64
#define DD 512
#define HH 8
#define HDIM 64
#define LL 4
#define FFD 2048
#define VV 128

#define NBLK 256
#define NTHR 512

// ---------------- threefry2x32 (20 rounds), matches JAX ----------------
__host__ __device__ inline uint32_t rotl32(uint32_t v, int n){ return (v << n) | (v >> (32 - n)); }

__host__ __device__ inline void tf2x32(uint32_t k0, uint32_t k1, uint32_t x0, uint32_t x1,
                                       uint32_t* o0, uint32_t* o1){
  uint32_t ks2 = k0 ^ k1 ^ 0x1BD11BDAu;
  x0 += k0; x1 += k1;
  x0 += x1; x1 = rotl32(x1,13); x1 ^= x0;
  x0 += x1; x1 = rotl32(x1,15); x1 ^= x0;
  x0 += x1; x1 = rotl32(x1,26); x1 ^= x0;
  x0 += x1; x1 = rotl32(x1, 6); x1 ^= x0;
  x0 += k1; x1 += ks2 + 1u;
  x0 += x1; x1 = rotl32(x1,17); x1 ^= x0;
  x0 += x1; x1 = rotl32(x1,29); x1 ^= x0;
  x0 += x1; x1 = rotl32(x1,16); x1 ^= x0;
  x0 += x1; x1 = rotl32(x1,24); x1 ^= x0;
  x0 += ks2; x1 += k0 + 2u;
  x0 += x1; x1 = rotl32(x1,13); x1 ^= x0;
  x0 += x1; x1 = rotl32(x1,15); x1 ^= x0;
  x0 += x1; x1 = rotl32(x1,26); x1 ^= x0;
  x0 += x1; x1 = rotl32(x1, 6); x1 ^= x0;
  x0 += k0; x1 += k1 + 3u;
  x0 += x1; x1 = rotl32(x1,17); x1 ^= x0;
  x0 += x1; x1 = rotl32(x1,29); x1 ^= x0;
  x0 += x1; x1 = rotl32(x1,16); x1 ^= x0;
  x0 += x1; x1 = rotl32(x1,24); x1 ^= x0;
  x0 += k1; x1 += ks2 + 4u;
  x0 += x1; x1 = rotl32(x1,13); x1 ^= x0;
  x0 += x1; x1 = rotl32(x1,15); x1 ^= x0;
  x0 += x1; x1 = rotl32(x1,26); x1 ^= x0;
  x0 += x1; x1 = rotl32(x1, 6); x1 ^= x0;
  x0 += ks2; x1 += k0 + 5u;
  *o0 = x0; *o1 = x1;
}

// ---------------- helpers ----------------
__device__ inline float dot_f4(const float* __restrict__ a, const float* __restrict__ w, int K){
  float acc = 0.f;
  const float4* a4 = (const float4*)a;
  const float4* w4 = (const float4*)w;
  int K4 = K >> 2;
  for (int k = 0; k < K4; ++k){
    float4 av = a4[k], wv = w4[k];
    acc = fmaf(av.x, wv.x, acc);
    acc = fmaf(av.y, wv.y, acc);
    acc = fmaf(av.z, wv.z, acc);
    acc = fmaf(av.w, wv.w, acc);
  }
  return acc;
}

// LayerNorm across a 512-thread block (one value per thread).
__device__ inline float block_ln(float v, float g, float bb, float* red){
  __syncthreads();
  float s = v;
  #pragma unroll
  for (int off = 32; off; off >>= 1) s += __shfl_xor(s, off);
  if ((threadIdx.x & 63) == 0) red[threadIdx.x >> 6] = s;
  __syncthreads();
  float mu = (red[0]+red[1]+red[2]+red[3]+red[4]+red[5]+red[6]+red[7]) * (1.0f/512.0f);
  float dv = v - mu;
  float sq = dv * dv;
  #pragma unroll
  for (int off = 32; off; off >>= 1) sq += __shfl_xor(sq, off);
  __syncthreads();
  if ((threadIdx.x & 63) == 0) red[threadIdx.x >> 6] = sq;
  __syncthreads();
  float var = (red[0]+red[1]+red[2]+red[3]+red[4]+red[5]+red[6]+red[7]) * (1.0f/512.0f);
  return dv * (1.0f / sqrtf(var + 1e-5f)) * g + bb;
}

// row reduction among the 128 threads (2 waves) owning row j (j = tid>>7); all 512 call.
__device__ inline float row_reduce(float v, int wid, int j, float* wred){
  #pragma unroll
  for (int off = 32; off; off >>= 1) v += __shfl_xor(v, off);
  if ((threadIdx.x & 63) == 0) wred[wid] = v;
  __syncthreads();
  float r = wred[2*j] + wred[2*j+1];
  __syncthreads();
  return r;
}

// ---------------- barrier v5: XCD-half-local tree + 2-flag handshake (monotonic) ----------
// Group g = bid&3 spans XCDs {g, g+4}; half h = m&1 is XCD-local (bid%8 = g or g+4).
// Layout: subcnt[gh][sub] @ gh*64+sub*16 ; halfcnt[gh] @ 1024+gh*16 ;
//         hflag[gh] @ 1280+gh*16 ; hgen[gh] @ 1536+gh*16.  All monotonic.
__device__ __forceinline__ void gbar(unsigned* bar, int g, int m, unsigned epoch){
  __syncthreads();
  if (threadIdx.x == 0){
    __builtin_amdgcn_fence(__ATOMIC_RELEASE, "agent");
    const int h   = m & 1;
    const int k   = m >> 1;      // 0..31 within half
    const int sub = k >> 3;      // 0..3
    const int gh  = g*2 + h;
    unsigned* subcnt  = bar + gh*64 + sub*16;
    unsigned* halfcnt = bar + 1024 + gh*16;
    unsigned* hflag   = bar + 1280 + gh*16;
    unsigned* peer    = bar + 1280 + (g*2 + (1-h))*16;
    unsigned* hgen    = bar + 1536 + gh*16;
    unsigned old = __hip_atomic_fetch_add(subcnt, 1u, __ATOMIC_RELAXED, __HIP_MEMORY_SCOPE_AGENT);
    if (old == 8u*epoch - 1u){
      unsigned o2 = __hip_atomic_fetch_add(halfcnt, 1u, __ATOMIC_RELAXED, __HIP_MEMORY_SCOPE_AGENT);
      if (o2 == 4u*epoch - 1u){
        __hip_atomic_store(hflag, epoch, __ATOMIC_RELAXED, __HIP_MEMORY_SCOPE_AGENT);
        while (__hip_atomic_load(peer, __ATOMIC_RELAXED, __HIP_MEMORY_SCOPE_AGENT) < epoch)
          __builtin_amdgcn_s_sleep(1);
        __hip_atomic_store(hgen, epoch, __ATOMIC_RELAXED, __HIP_MEMORY_SCOPE_AGENT);
      }
    }
    while (__hip_atomic_load(hgen, __ATOMIC_RELAXED, __HIP_MEMORY_SCOPE_AGENT) < epoch)
      __builtin_amdgcn_s_sleep(1);
    __builtin_amdgcn_fence(__ATOMIC_ACQUIRE, "agent");
  }
  __syncthreads();
}

// ---------------- setup kernels ----------------
__global__ void k_tables(float* __restrict__ cosb, float* __restrict__ sinb){
  int tid = blockIdx.x * blockDim.x + threadIdx.x;  // TT*256
  int p = tid >> 8, i = tid & 255;
  float sv = (2.0f * (float)i + 204.8f) / 716.8f;
  float scale = powf(sv, (float)p / 16.0f);
  float invf = 1.0f / powf(10000.0f, (float)i / 256.0f);
  float ang = (float)p * invf;
  cosb[tid] = cosf(ang) * scale;
  sinb[tid] = sinf(ang) * scale;
}

__global__ void k_ca1(const float* __restrict__ mol, const float* __restrict__ w,
                      const float* __restrict__ bias, float* __restrict__ tmp){
  int tid = blockIdx.x * blockDim.x + threadIdx.x;  // LL*BB*DD
  int l = tid >> 14; int r = tid & 16383; int b = r >> 9; int d = r & 511;
  const float* wr = w + (size_t)l*3*DD*DD + (size_t)(2*DD + d)*DD;
  tmp[tid] = bias[l*3*DD + 2*DD + d] + dot_f4(mol + (size_t)b*DD, wr, DD);
}

__global__ void k_ca2(const float* __restrict__ tmp, const float* __restrict__ w,
                      const float* __restrict__ bias, float* __restrict__ cac){
  int tid = blockIdx.x * blockDim.x + threadIdx.x;  // LL*BB*DD
  int l = tid >> 14; int r = tid & 16383; int b = r >> 9; int d = r & 511;
  const float* wr = w + (size_t)l*DD*DD + (size_t)d*DD;
  cac[tid] = bias[l*DD + d] + dot_f4(tmp + ((size_t)l*BB + b)*DD, wr, DD);
}

__global__ void k_binit(unsigned* __restrict__ bar, int* __restrict__ pred){
  int tid = threadIdx.x;            // 1024 threads
  bar[tid] = 0u;
  bar[tid + 1024] = 0u;
  pred[tid]        = ((tid & (TT-1)) == 0) ? 1 : 0;
  pred[tid + 1024] = (((tid + 1024) & (TT-1)) == 0) ? 1 : 0;
}

// k32-pack: in [L][N][K] row-major -> out [L][K/32][N][32]
__global__ void k_pack32(const float* __restrict__ in, float* __restrict__ out,
                         int N, int K, int total){
  int tid = blockIdx.x * blockDim.x + threadIdx.x;
  if (tid >= total) return;
  int S = N * K;
  int l = tid / S, r = tid - l*S;
  int k32 = r / (32*N);
  int r2 = r - k32*32*N;
  int n = r2 >> 5, ku = r2 & 31;
  out[tid] = in[(size_t)l*S + (size_t)n*K + k32*32 + ku];
}

// consume one cell (8 float4 = 32 k) into 8 row accumulators, k-ascending per row
#define CELL8(WARR, KOFF)                                                     \
  _Pragma("unroll")                                                           \
  for (int q = 0; q < 8; ++q){                                                \
    float4 w = WARR[q];                                                       \
    const int kk = (KOFF) + q*4;                                              \
    _Pragma("unroll")                                                         \
    for (int r_ = 0; r_ < 8; ++r_){                                           \
      float4 x = *(const float4*)&sxp[r_*512 + kk];                           \
      a[r_]=fmaf(w.x,x.x,a[r_]); a[r_]=fmaf(w.y,x.y,a[r_]);                   \
      a[r_]=fmaf(w.z,x.z,a[r_]); a[r_]=fmaf(w.w,x.w,a[r_]);                   \
    }                                                                         \
  }

// ---------------- persistent decode kernel ----------------
struct KParams {
  const float *emb, *sab, *sob, *f1b, *f2b;
  const float *g1,*b1,*g2,*b2,*g3,*b3,*fg,*fb;
  const float *o1b,*o2b,*o3w,*o3b;
  const float *cosb,*sinb,*cac;
  const float *sawP,*sowP,*f1wP,*f2wP,*o1wP,*o2wP;   // k32-packed [K/32][N][32]
  float *kc,*vc,*xl,*qb,*at,*ao,*x2,*fo,*h1,*xf,*hh1,*hh2,*ps3;
  int *pred;
  unsigned *bar;
};

__global__ __launch_bounds__(NTHR) void k_persist(KParams P){
  const int bid = blockIdx.x, tid = threadIdx.x;
  const int g = bid & 3;          // group spans XCDs {g, g+4} under %8 round-robin
  const int m = bid >> 2;         // member 0..63
  const int wid = tid >> 6, lane = tid & 63;
  __shared__ __align__(16) float smem[17472];   // ~70 KB
  unsigned epoch = 0;

  for (int t = 1; t < TT; ++t){
    const int pp = t - 1;

    for (int l = 0; l < LL; ++l){
      // ================= S1: build x_l (8 rows) + QKV (24 blocks x 64 cols x 8 rows) ======
      if (m < 24){
        float* sx   = smem;          // [8][512]
        float* part = smem + 4096;   // [8][8][64]
        float* srow = smem + 8192;   // [8][2]
        if (l == 0){
          #pragma unroll
          for (int it = 0; it < 2; ++it){
            int j = it*4 + (tid >> 7), d4 = (tid & 127) * 4;
            int rb = g*8 + j;
            int tok = P.pred[rb*TT + pp];
            #pragma unroll
            for (int e = d4; e < d4 + 4; e += 2){
              int i = e >> 1;
              float c = P.cosb[pp*256 + i], s = P.sinb[pp*256 + i];
              float e0 = P.emb[(size_t)tok*DD + e];
              float e1 = P.emb[(size_t)tok*DD + e + 1];
              sx[j*512 + e]     = fmaf(e0, c, -(e1*s));
              sx[j*512 + e + 1] = fmaf(e1, c, e0*s);
            }
          }
        } else {
          if (tid < 8){
            float aa = 0.f, bq = 0.f;
            const float* pr = P.ps3 + (size_t)(g*8 + tid)*64;
            for (int s = 0; s < 32; ++s){ aa += pr[s*2]; bq += pr[s*2+1]; }
            float mu = aa * (1.0f/512.0f);
            float var = bq * (1.0f/512.0f) - mu*mu;
            srow[tid*2]   = mu;
            srow[tid*2+1] = 1.0f / sqrtf(var + 1e-5f);
          }
          __syncthreads();
          #pragma unroll
          for (int it = 0; it < 2; ++it){
            int j = it*4 + (tid >> 7), d4 = (tid & 127) * 4;
            int rb = g*8 + j;
            float mu = srow[j*2], rs = srow[j*2+1];
            float4 xv = *(const float4*)&P.x2[(size_t)rb*DD + d4];
            float4 fv = *(const float4*)&P.fo[(size_t)rb*DD + d4];
            const float* g3r = P.g3 + (size_t)(l-1)*DD;
            const float* b3r = P.b3 + (size_t)(l-1)*DD;
            float yv[4] = {xv.x+fv.x, xv.y+fv.y, xv.z+fv.z, xv.w+fv.w};
            #pragma unroll
            for (int i = 0; i < 4; ++i)
              sx[j*512 + d4 + i] = (yv[i]-mu)*rs*g3r[d4+i] + b3r[d4+i];
          }
        }
        __syncthreads();
        if (m == 0){   // materialize x_l (all 8 rows)
          #pragma unroll
          for (int it = 0; it < 2; ++it){
            int j = it*4 + (tid >> 7), d4 = (tid & 127) * 4;
            *(float4*)&P.xl[(size_t)(g*8+j)*DD + d4] = *(float4*)&sx[j*512 + d4];
          }
        }
        // qkv dot
        const int n0 = m*64;
        const float4* wb0 = (const float4*)P.sawP + ((size_t)l*16 + wid*2)*(1536*8)
                          + (size_t)(n0 + lane)*8;
        const float4* wb1 = wb0 + 1536*8;
        float4 w0[8], w1[8];
        #pragma unroll
        for (int q = 0; q < 8; ++q) w0[q] = wb0[q];
        #pragma unroll
        for (int q = 0; q < 8; ++q) w1[q] = wb1[q];
        float a[8] = {0.f,0.f,0.f,0.f,0.f,0.f,0.f,0.f};
        const float* sxp = sx;
        const int kb = wid*64;
        CELL8(w0, kb);
        CELL8(w1, kb + 32);
        #pragma unroll
        for (int r_ = 0; r_ < 8; ++r_) part[(wid*8 + r_)*64 + lane] = a[r_];
        __syncthreads();
        {
          int jr = tid >> 6, nl = tid & 63;
          int n = n0 + nl, rb2 = g*8 + jr;
          float s = P.sab[l*1536 + n];
          #pragma unroll
          for (int w = 0; w < 8; ++w) s += part[(w*8+jr)*64 + nl];
          if (n < DD){
            P.qb[(size_t)rb2*DD + n] = s;
          } else if (n < 2*DD){
            int h = (n - DD) >> 6, hd = (n - DD) & 63;
            P.kc[((((size_t)l*BB + rb2)*HH + h)*TT + pp)*HDIM + hd] = s;
          } else {
            int h = (n - 2*DD) >> 6, hd = (n - 2*DD) & 63;
            P.vc[((((size_t)l*BB + rb2)*HH + h)*TT + pp)*HDIM + hd] = s;
          }
        }
      }
      gbar(P.bar, g, m, ++epoch);

      // ================= S2: attention (64 blocks = 8 rows x 8 heads, 1 wave) ============
      {
        int bl = m >> 3, h = m & 7, rb = g*8 + bl;
        float* qs = smem; float* ps = smem + 64;
        if (tid < 64) qs[tid] = P.qb[(size_t)rb*DD + h*HDIM + tid];
        __syncthreads();
        if (tid < 64){
          const float* kb = P.kc + (((size_t)l*BB + rb)*HH + h)*TT*HDIM;
          float s = -INFINITY;
          if (lane <= pp && P.pred[rb*TT + lane] != 0){
            const float* kr = kb + lane*HDIM;
            float acc = 0.f;
            #pragma unroll
            for (int k2 = 0; k2 < HDIM; ++k2) acc = fmaf(qs[k2], kr[k2], acc);
            s = acc * 0.125f;
          }
          float mx = s;
          #pragma unroll
          for (int off = 32; off; off >>= 1) mx = fmaxf(mx, __shfl_xor(mx, off));
          float e = (s == -INFINITY) ? 0.f : expf(s - mx);
          float sum = e;
          #pragma unroll
          for (int off = 32; off; off >>= 1) sum += __shfl_xor(sum, off);
          ps[lane] = e / sum;
          const float* vb = P.vc + (((size_t)l*BB + rb)*HH + h)*TT*HDIM;
          float o = 0.f;
          int jj = 0;
          for (; jj + 8 <= t; jj += 8){
            float vv[8];
            #pragma unroll
            for (int u = 0; u < 8; ++u) vv[u] = vb[(jj+u)*HDIM + lane];
            #pragma unroll
            for (int u = 0; u < 8; ++u) o = fmaf(ps[jj+u], vv[u], o);
          }
          for (; jj <= pp; ++jj) o = fmaf(ps[jj], vb[jj*HDIM + lane], o);
          P.at[(size_t)rb*DD + h*HDIM + lane] = o;
        }
      }
      gbar(P.bar, g, m, ++epoch);

      // ================= S3: oproj (32 blocks x 16 cols x 8 rows) =================
      if (m < 32){
        float* ats  = smem;          // [8][512]
        float* part = smem + 4096;   // [8][128]
        #pragma unroll
        for (int q = 0; q < 2; ++q){
          int fi = tid + q*512;               // float4 index over [8][128]
          int j = fi >> 7, c4 = fi & 127;
          *(float4*)&ats[j*512 + c4*4] = *(const float4*)&P.at[(size_t)(g*8+j)*DD + c4*4];
        }
        __syncthreads();
        const int n0 = m*16;
        const int jb = lane >> 4, nc = lane & 15;
        const float4* wb0 = (const float4*)P.sowP + ((size_t)l*16 + wid*2)*(512*8)
                          + (size_t)(n0 + nc)*8;
        const float4* wb1 = wb0 + 512*8;
        float4 w0[8], w1[8];
        #pragma unroll
        for (int q = 0; q < 8; ++q) w0[q] = wb0[q];
        #pragma unroll
        for (int q = 0; q < 8; ++q) w1[q] = wb1[q];
        float ac0 = 0.f, ac1 = 0.f;     // rows jb and jb+4
        const int kb = wid*64;
        #pragma unroll
        for (int q = 0; q < 8; ++q){
          float4 w = w0[q];
          float4 xa = *(const float4*)&ats[jb*512 + kb + q*4];
          float4 xb = *(const float4*)&ats[(jb+4)*512 + kb + q*4];
          ac0=fmaf(w.x,xa.x,ac0); ac0=fmaf(w.y,xa.y,ac0); ac0=fmaf(w.z,xa.z,ac0); ac0=fmaf(w.w,xa.w,ac0);
          ac1=fmaf(w.x,xb.x,ac1); ac1=fmaf(w.y,xb.y,ac1); ac1=fmaf(w.z,xb.z,ac1); ac1=fmaf(w.w,xb.w,ac1);
        }
        #pragma unroll
        for (int q = 0; q < 8; ++q){
          float4 w = w1[q];
          float4 xa = *(const float4*)&ats[jb*512 + kb + 32 + q*4];
          float4 xb = *(const float4*)&ats[(jb+4)*512 + kb + 32 + q*4];
          ac0=fmaf(w.x,xa.x,ac0); ac0=fmaf(w.y,xa.y,ac0); ac0=fmaf(w.z,xa.z,ac0); ac0=fmaf(w.w,xa.w,ac0);
          ac1=fmaf(w.x,xb.x,ac1); ac1=fmaf(w.y,xb.y,ac1); ac1=fmaf(w.z,xb.z,ac1); ac1=fmaf(w.w,xb.w,ac1);
        }
        part[wid*128 + jb*16 + nc]       = ac0;
        part[wid*128 + (jb+4)*16 + nc]   = ac1;
        __syncthreads();
        if (tid < 128){
          int jb2 = tid >> 4, nc2 = tid & 15, n = n0 + nc2;
          float s = P.sob[l*DD + n];
          #pragma unroll
          for (int w = 0; w < 8; ++w) s += part[w*128 + jb2*16 + nc2];
          P.ao[(size_t)(g*8+jb2)*DD + n] = s;
        }
      }
      gbar(P.bar, g, m, ++epoch);

      // ================= S4: ln1+ln2 (redundant, 2 passes) + FF1 (32 blocks x 64 cols x 8 rows)
      if (m < 32){
        float* sx2  = smem;          // [8][512]
        float* part = smem + 4096;   // [8][8][64]
        float* wred = smem + 8192;   // [8]
        #pragma unroll
        for (int it = 0; it < 2; ++it){
          int j = tid >> 7, d4 = (tid & 127) * 4;
          int jr = it*4 + j;
          int rb = g*8 + jr;
          float4 xlv = *(const float4*)&P.xl[(size_t)rb*DD + d4];
          float4 aov = *(const float4*)&P.ao[(size_t)rb*DD + d4];
          float y[4] = {xlv.x+aov.x, xlv.y+aov.y, xlv.z+aov.z, xlv.w+aov.w};
          float s = ((y[0]+y[1])+y[2])+y[3];
          float mu = row_reduce(s, wid, j, wred) * (1.0f/512.0f);
          float dv[4], sq = 0.f;
          #pragma unroll
          for (int i = 0; i < 4; ++i){ dv[i] = y[i]-mu; sq += dv[i]*dv[i]; }
          float rs = 1.0f / sqrtf(row_reduce(sq, wid, j, wred) * (1.0f/512.0f) + 1e-5f);
          float z[4];
          #pragma unroll
          for (int i = 0; i < 4; ++i){
            int d = d4 + i;
            z[i] = dv[i]*rs*P.g1[l*DD+d] + P.b1[l*DD+d] + P.cac[((size_t)l*BB + rb)*DD + d];
          }
          float s2 = ((z[0]+z[1])+z[2])+z[3];
          float mu2 = row_reduce(s2, wid, j, wred) * (1.0f/512.0f);
          float dz[4], sq2 = 0.f;
          #pragma unroll
          for (int i = 0; i < 4; ++i){ dz[i] = z[i]-mu2; sq2 += dz[i]*dz[i]; }
          float rs2 = 1.0f / sqrtf(row_reduce(sq2, wid, j, wred) * (1.0f/512.0f) + 1e-5f);
          #pragma unroll
          for (int i = 0; i < 4; ++i){
            int d = d4 + i;
            float x2v = dz[i]*rs2*P.g2[l*DD+d] + P.b2[l*DD+d];
            sx2[jr*512 + d] = x2v;
          }
        }
        __syncthreads();
        if (m == 0){
          #pragma unroll
          for (int it = 0; it < 2; ++it){
            int jr = it*4 + (tid >> 7), d4 = (tid & 127) * 4;
            *(float4*)&P.x2[(size_t)(g*8+jr)*DD + d4] = *(float4*)&sx2[jr*512 + d4];
          }
        }
        // ff1 dot
        const int n0 = m*64;
        const float4* wb0 = (const float4*)P.f1wP + ((size_t)l*16 + wid*2)*(2048*8)
                          + (size_t)(n0 + lane)*8;
        const float4* wb1 = wb0 + 2048*8;
        float4 w0[8], w1[8];
        #pragma unroll
        for (int q = 0; q < 8; ++q) w0[q] = wb0[q];
        #pragma unroll
        for (int q = 0; q < 8; ++q) w1[q] = wb1[q];
        float a[8] = {0.f,0.f,0.f,0.f,0.f,0.f,0.f,0.f};
        const float* sxp = sx2;
        const int kb = wid*64;
        CELL8(w0, kb);
        CELL8(w1, kb + 32);
        #pragma unroll
        for (int r_ = 0; r_ < 8; ++r_) part[(wid*8 + r_)*64 + lane] = a[r_];
        __syncthreads();
        {
          int jr = tid >> 6, nl = tid & 63;
          int n = n0 + nl;
          float v = P.f1b[l*FFD + n];
          #pragma unroll
          for (int w = 0; w < 8; ++w) v += part[(w*8+jr)*64 + nl];
          P.h1[(size_t)(g*8+jr)*FFD + n] = v / (1.0f + expf(-v));
        }
      }
      gbar(P.bar, g, m, ++epoch);

      // ================= S5: FF2 (32 blocks x 16 cols x 8 rows) + ln3 partials ===========
      if (m < 32){
        float* sh1  = smem;          // [8][2048] = 64 KB
        float* part = smem + 16384;  // [8][128]
        #pragma unroll
        for (int q = 0; q < 8; ++q){
          int fi = tid + q*512;               // float4 index over [8][512]
          int j = fi >> 9, c4 = fi & 511;
          *(float4*)&sh1[j*2048 + c4*4] = *(const float4*)&P.h1[(size_t)(g*8+j)*FFD + c4*4];
        }
        __syncthreads();
        const int n0 = m*16;
        const int jb = lane >> 4, nc = lane & 15;
        const float4* base = (const float4*)P.f2wP + ((size_t)l*64 + wid*8)*(512*8)
                           + (size_t)(n0 + nc)*8;
        float ac0 = 0.f, ac1 = 0.f;    // rows jb, jb+4
        #pragma unroll
        for (int cc = 0; cc < 4; ++cc){
          const float4* b0 = base + (size_t)(cc*2)*(512*8);
          const float4* b1 = b0 + 512*8;
          float4 w0[8], w1[8];
          #pragma unroll
          for (int q = 0; q < 8; ++q) w0[q] = b0[q];
          #pragma unroll
          for (int q = 0; q < 8; ++q) w1[q] = b1[q];
          const int kb = wid*256 + cc*64;
          #pragma unroll
          for (int q = 0; q < 8; ++q){
            float4 w = w0[q];
            float4 xa = *(const float4*)&sh1[jb*2048 + kb + q*4];
            float4 xb = *(const float4*)&sh1[(jb+4)*2048 + kb + q*4];
            ac0=fmaf(w.x,xa.x,ac0); ac0=fmaf(w.y,xa.y,ac0); ac0=fmaf(w.z,xa.z,ac0); ac0=fmaf(w.w,xa.w,ac0);
            ac1=fmaf(w.x,xb.x,ac1); ac1=fmaf(w.y,xb.y,ac1); ac1=fmaf(w.z,xb.z,ac1); ac1=fmaf(w.w,xb.w,ac1);
          }
          #pragma unroll
          for (int q = 0; q < 8; ++q){
            float4 w = w1[q];
            float4 xa = *(const float4*)&sh1[jb*2048 + kb + 32 + q*4];
            float4 xb = *(const float4*)&sh1[(jb+4)*2048 + kb + 32 + q*4];
            ac0=fmaf(w.x,xa.x,ac0); ac0=fmaf(w.y,xa.y,ac0); ac0=fmaf(w.z,xa.z,ac0); ac0=fmaf(w.w,xa.w,ac0);
            ac1=fmaf(w.x,xb.x,ac1); ac1=fmaf(w.y,xb.y,ac1); ac1=fmaf(w.z,xb.z,ac1); ac1=fmaf(w.w,xb.w,ac1);
          }
        }
        part[wid*128 + jb*16 + nc]     = ac0;
        part[wid*128 + (jb+4)*16 + nc] = ac1;
        __syncthreads();
        if (tid < 128){
          int jb2 = tid >> 4, nc2 = tid & 15, n = n0 + nc2;
          int rb2 = g*8 + jb2;
          float val = P.f2b[l*DD + n];
          #pragma unroll
          for (int w = 0; w < 8; ++w) val += part[w*128 + jb2*16 + nc2];
          P.fo[(size_t)rb2*DD + n] = val;
          float y = P.x2[(size_t)rb2*DD + n] + val;
          float s1 = y, sq = y*y;
          #pragma unroll
          for (int off = 1; off < 16; off <<= 1){
            s1 += __shfl_xor(s1, off);
            sq += __shfl_xor(sq, off);
          }
          if (nc2 == 0){
            P.ps3[(size_t)(rb2*32 + m)*2]     = s1;
            P.ps3[(size_t)(rb2*32 + m)*2 + 1] = sq;
          }
        }
      }
      gbar(P.bar, g, m, ++epoch);
    }

    // ================= S6: final ln3 + fn ln (8 row blocks) =================
    if (m < 8){
      int rb = g*8 + m, d = tid;
      float y = P.x2[(size_t)rb*DD + d] + P.fo[(size_t)rb*DD + d];
      float xv = block_ln(y, P.g3[3*DD + d], P.b3[3*DD + d], smem);
      float o  = block_ln(xv, P.fg[d], P.fb[d], smem);
      P.xf[(size_t)rb*DD + d] = o;
    }
    gbar(P.bar, g, m, ++epoch);

    // ================= S7: head1 (32 blocks x 32 cols x 8 rows) =================
    if (m < 32){
      float* sxf  = smem;          // [8][512]
      float* part = smem + 4096;   // [8][8][32]
      #pragma unroll
      for (int q = 0; q < 2; ++q){
        int fi = tid + q*512;
        int j = fi >> 7, c4 = fi & 127;
        *(float4*)&sxf[j*512 + c4*4] = *(const float4*)&P.xf[(size_t)(g*8+j)*DD + c4*4];
      }
      __syncthreads();
      const int n0 = m*32;
      const int jh = lane >> 5, nc = lane & 31;
      const float4* wb0 = (const float4*)P.o1wP + (size_t)(wid*2)*(1024*8)
                        + (size_t)(n0 + nc)*8;
      const float4* wb1 = wb0 + 1024*8;
      float4 w0[8], w1[8];
      #pragma unroll
      for (int q = 0; q < 8; ++q) w0[q] = wb0[q];
      #pragma unroll
      for (int q = 0; q < 8; ++q) w1[q] = wb1[q];
      float ac[4] = {0.f,0.f,0.f,0.f};    // rows jh + 2*ai
      const int kb = wid*64;
      #pragma unroll
      for (int q = 0; q < 8; ++q){
        float4 w = w0[q];
        #pragma unroll
        for (int ai = 0; ai < 4; ++ai){
          float4 x = *(const float4*)&sxf[(jh+2*ai)*512 + kb + q*4];
          ac[ai]=fmaf(w.x,x.x,ac[ai]); ac[ai]=fmaf(w.y,x.y,ac[ai]);
          ac[ai]=fmaf(w.z,x.z,ac[ai]); ac[ai]=fmaf(w.w,x.w,ac[ai]);
        }
      }
      #pragma unroll
      for (int q = 0; q < 8; ++q){
        float4 w = w1[q];
        #pragma unroll
        for (int ai = 0; ai < 4; ++ai){
          float4 x = *(const float4*)&sxf[(jh+2*ai)*512 + kb + 32 + q*4];
          ac[ai]=fmaf(w.x,x.x,ac[ai]); ac[ai]=fmaf(w.y,x.y,ac[ai]);
          ac[ai]=fmaf(w.z,x.z,ac[ai]); ac[ai]=fmaf(w.w,x.w,ac[ai]);
        }
      }
      #pragma unroll
      for (int ai = 0; ai < 4; ++ai) part[(wid*8 + (jh+2*ai))*32 + nc] = ac[ai];
      __syncthreads();
      if (tid < 256){
        int row = tid >> 5, nc2 = tid & 31, n = n0 + nc2;
        float aa = P.o1b[n];
        #pragma unroll
        for (int w = 0; w < 8; ++w) aa += part[(w*8+row)*32 + nc2];
        P.hh1[(size_t)(g*8+row)*1024 + n] = 0.5f * aa * (1.0f + erff(aa / 1.41421356237309504880f));
      }
    }
    gbar(P.bar, g, m, ++epoch);

    // ================= S8: head2 (32 blocks x 32 cols x 8 rows, K=1024) =================
    if (m < 32){
      float* sh   = smem;          // [8][1024]
      float* part = smem + 8192;   // [8][8][32]
      #pragma unroll
      for (int q = 0; q < 4; ++q){
        int fi = tid + q*512;
        int j = fi >> 8, c4 = fi & 255;
        *(float4*)&sh[j*1024 + c4*4] = *(const float4*)&P.hh1[(size_t)(g*8+j)*1024 + c4*4];
      }
      __syncthreads();
      const int n0 = m*32;
      const int jh = lane >> 5, nc = lane & 31;
      const float4* base = (const float4*)P.o2wP + (size_t)(wid*4)*(1024*8)
                         + (size_t)(n0 + nc)*8;
      float ac[4] = {0.f,0.f,0.f,0.f};
      #pragma unroll
      for (int cc = 0; cc < 2; ++cc){
        const float4* b0 = base + (size_t)(cc*2)*(1024*8);
        const float4* b1 = b0 + 1024*8;
        float4 w0[8], w1[8];
        #pragma unroll
        for (int q = 0; q < 8; ++q) w0[q] = b0[q];
        #pragma unroll
        for (int q = 0; q < 8; ++q) w1[q] = b1[q];
        const int kb = wid*128 + cc*64;
        #pragma unroll
        for (int q = 0; q < 8; ++q){
          float4 w = w0[q];
          #pragma unroll
          for (int ai = 0; ai < 4; ++ai){
            float4 x = *(const float4*)&sh[(jh+2*ai)*1024 + kb + q*4];
            ac[ai]=fmaf(w.x,x.x,ac[ai]); ac[ai]=fmaf(w.y,x.y,ac[ai]);
            ac[ai]=fmaf(w.z,x.z,ac[ai]); ac[ai]=fmaf(w.w,x.w,ac[ai]);
          }
        }
        #pragma unroll
        for (int q = 0; q < 8; ++q){
          float4 w = w1[q];
          #pragma unroll
          for (int ai = 0; ai < 4; ++ai){
            float4 x = *(const float4*)&sh[(jh+2*ai)*1024 + kb + 32 + q*4];
            ac[ai]=fmaf(w.x,x.x,ac[ai]); ac[ai]=fmaf(w.y,x.y,ac[ai]);
            ac[ai]=fmaf(w.z,x.z,ac[ai]); ac[ai]=fmaf(w.w,x.w,ac[ai]);
          }
        }
      }
      #pragma unroll
      for (int ai = 0; ai < 4; ++ai) part[(wid*8 + (jh+2*ai))*32 + nc] = ac[ai];
      __syncthreads();
      if (tid < 256){
        int row = tid >> 5, nc2 = tid & 31, n = n0 + nc2;
        float aa = P.o2b[n];
        #pragma unroll
        for (int w = 0; w < 8; ++w) aa += part[(w*8+row)*32 + nc2];
        P.hh2[(size_t)(g*8+row)*1024 + n] = 0.5f * aa * (1.0f + erff(aa / 1.41421356237309504880f));
      }
    }
    gbar(P.bar, g, m, ++epoch);

    // ================= S9: sample (8 row blocks; exact r14 math) =================
    if (m < 8){
      int rb = g*8 + m, v = tid;
      float* hrow = smem;                 // 1024
      float* red  = smem + 1024;          // 8
      int*   redi = (int*)(smem + 1032);  // 2
      for (int k = tid; k < 1024; k += NTHR) hrow[k] = P.hh2[(size_t)rb*1024 + k];
      __syncthreads();
      float sv = 0.f;
      if (tid < 128){
        float acc = P.o3b[v] + dot_f4(hrow, P.o3w + (size_t)v*1024, 1024);
        sv = acc / 0.1f;
      }
      float mx = (tid < 128) ? sv : -INFINITY;
      #pragma unroll
      for (int off = 32; off; off >>= 1) mx = fmaxf(mx, __shfl_xor(mx, off));
      __syncthreads();
      if (tid < 128 && (tid & 63) == 0) red[tid >> 6] = mx;
      __syncthreads();
      mx = fmaxf(red[0], red[1]);
      float e = (tid < 128) ? expf(sv - mx) : 0.f;
      float sum = e;
      #pragma unroll
      for (int off = 32; off; off >>= 1) sum += __shfl_xor(sum, off);
      __syncthreads();
      if (tid < 128 && (tid & 63) == 0) red[tid >> 6] = sum;
      __syncthreads();
      sum = red[0] + red[1];
      float bv = -INFINITY; int bi = 0x7fffffff;
      if (tid < 128){
        float lp = (sv - mx) - logf(sum);
        uint32_t kk0, kk1, o0, o1;
        tf2x32(0u, 1u, 0u, (uint32_t)t, &kk0, &kk1);
        tf2x32(kk0, kk1, 0u, (uint32_t)(rb*VV + v), &o0, &o1);
        uint32_t bits = o0 ^ o1;
        float u = __uint_as_float((bits >> 9) | 0x3F800000u) - 1.0f;
        float gg = -logf(-logf(u + 1e-9f) + 1e-9f);
        bv = lp + gg; bi = v;
      }
      #pragma unroll
      for (int off = 32; off; off >>= 1){
        float ov = __shfl_xor(bv, off);
        int   oi = __shfl_xor(bi, off);
        if (ov > bv || (ov == bv && oi < bi)){ bv = ov; bi = oi; }
      }
      __syncthreads();
      if (tid < 128 && (tid & 63) == 0){ red[tid >> 6] = bv; redi[tid >> 6] = bi; }
      __syncthreads();
      if (tid == 0){
        float v0 = red[0], v1 = red[1]; int i0 = redi[0], i1 = redi[1];
        P.pred[rb*TT + t] = (v1 > v0 || (v1 == v0 && i1 < i0)) ? i1 : i0;
      }
    }
    gbar(P.bar, g, m, ++epoch);
  }
}

// ---------------- host ----------------
extern "C" void kernel_launch(void* const* d_in, const int* in_sizes, int n_in,
                              void* d_out, int out_size, void* d_ws, size_t ws_size,
                              hipStream_t stream){
  (void)in_sizes; (void)n_in; (void)out_size; (void)ws_size;
  const float* mol      = (const float*)d_in[1];
  const float* sa_in_w  = (const float*)d_in[3];
  const float* sa_out_w = (const float*)d_in[5];
  const float* ca_in_w  = (const float*)d_in[7];
  const float* ca_in_b  = (const float*)d_in[8];
  const float* ca_out_w = (const float*)d_in[9];
  const float* ca_out_b = (const float*)d_in[10];
  const float* ff_w1    = (const float*)d_in[11];
  const float* ff_w2    = (const float*)d_in[13];
  const float* out_w1   = (const float*)d_in[23];
  const float* out_w2   = (const float*)d_in[25];

  KParams P;
  P.emb = (const float*)d_in[2];
  P.sab = (const float*)d_in[4];
  P.sob = (const float*)d_in[6];
  P.f1b = (const float*)d_in[12];
  P.f2b = (const float*)d_in[14];
  P.g1  = (const float*)d_in[15];
  P.b1  = (const float*)d_in[16];
  P.g2  = (const float*)d_in[17];
  P.b2  = (const float*)d_in[18];
  P.g3  = (const float*)d_in[19];
  P.b3  = (const float*)d_in[20];
  P.fg  = (const float*)d_in[21];
  P.fb  = (const float*)d_in[22];
  P.o1b = (const float*)d_in[24];
  P.o2b = (const float*)d_in[26];
  P.o3w = (const float*)d_in[27];
  P.o3b = (const float*)d_in[28];

  unsigned* bar = (unsigned*)d_ws;          // 2048 uints
  float* ws = (float*)d_ws + 2048;
  float* cosb   = ws;                       // 16384
  float* sinb   = cosb + 16384;             // 16384
  float* ca_tmp = sinb + 16384;             // 65536
  float* cac    = ca_tmp + 65536;           // 65536
  float* kc     = cac + 65536;              // 4194304
  float* vc     = kc + 4194304;             // 4194304
  float* xl     = vc + 4194304;             // 16384
  float* qb     = xl + 16384;               // 16384
  float* at     = qb + 16384;               // 16384
  float* ao     = at + 16384;               // 16384
  float* x2     = ao + 16384;               // 16384
  float* fo     = x2 + 16384;               // 16384
  float* h1     = fo + 16384;               // 65536
  float* xf     = h1 + 65536;               // 16384
  float* hh1    = xf + 16384;               // 32768
  float* hh2    = hh1 + 32768;              // 32768
  float* ps3    = hh2 + 32768;              // 2048
  float* sawP   = ps3 + 2048;               // 3145728
  float* sowP   = sawP + 3145728;           // 1048576
  float* f1wP   = sowP + 1048576;           // 4194304
  float* f2wP   = f1wP + 4194304;           // 4194304
  float* o1wP   = f2wP + 4194304;           // 524288
  float* o2wP   = o1wP + 524288;            // 1048576

  P.cosb = cosb; P.sinb = sinb; P.cac = cac;
  P.kc = kc; P.vc = vc; P.xl = xl; P.qb = qb; P.at = at; P.ao = ao;
  P.x2 = x2; P.fo = fo; P.h1 = h1; P.xf = xf; P.hh1 = hh1; P.hh2 = hh2;
  P.ps3 = ps3;
  P.sawP = sawP; P.sowP = sowP; P.f1wP = f1wP; P.f2wP = f2wP;
  P.o1wP = o1wP; P.o2wP = o2wP;
  P.pred = (int*)d_out;
  P.bar = bar;

  k_binit<<<1, 1024, 0, stream>>>(bar, P.pred);
  k_tables<<<64, 256, 0, stream>>>(cosb, sinb);
  k_ca1<<<256, 256, 0, stream>>>(mol, ca_in_w, ca_in_b, ca_tmp);
  k_ca2<<<256, 256, 0, stream>>>(ca_tmp, ca_out_w, ca_out_b, cac);

  // k32-pack all streamed weights: [L][N][K] -> [L][K/32][N][32]
  {
    int t1 = 4*1536*512;  k_pack32<<<(t1+255)/256, 256, 0, stream>>>(sa_in_w,  sawP, 1536, 512,  t1);
    int t2 = 4*512*512;   k_pack32<<<(t2+255)/256, 256, 0, stream>>>(sa_out_w, sowP,  512, 512,  t2);
    int t3 = 4*2048*512;  k_pack32<<<(t3+255)/256, 256, 0, stream>>>(ff_w1,    f1wP, 2048, 512,  t3);
    int t4 = 4*512*2048;  k_pack32<<<(t4+255)/256, 256, 0, stream>>>(ff_w2,    f2wP,  512, 2048, t4);
    int t5 = 1024*512;    k_pack32<<<(t5+255)/256, 256, 0, stream>>>(out_w1,   o1wP, 1024, 512,  t5);
    int t6 = 1024*1024;   k_pack32<<<(t6+255)/256, 256, 0, stream>>>(out_w2,   o2wP, 1024, 1024, t6);
  }

  k_persist<<<NBLK, NTHR, 0, stream>>>(P);
}

// Round 17
// 23348.827 us; speedup vs baseline: 1.7921x; 1.0608x over previous
//
#include <hip/hip_runtime.h>
#include <stdint.h>
#include <stddef.h>

#define BB 32
#define TT 64
#define DD 512
#define HH 8
#define HDIM 64
#define LL 4
#define FFD 2048
#define VV 128

#define NBLK 256
#define NTHR 512

// ---------------- threefry2x32 (20 rounds), matches JAX ----------------
__host__ __device__ inline uint32_t rotl32(uint32_t v, int n){ return (v << n) | (v >> (32 - n)); }

__host__ __device__ inline void tf2x32(uint32_t k0, uint32_t k1, uint32_t x0, uint32_t x1,
                                       uint32_t* o0, uint32_t* o1){
  uint32_t ks2 = k0 ^ k1 ^ 0x1BD11BDAu;
  x0 += k0; x1 += k1;
  x0 += x1; x1 = rotl32(x1,13); x1 ^= x0;
  x0 += x1; x1 = rotl32(x1,15); x1 ^= x0;
  x0 += x1; x1 = rotl32(x1,26); x1 ^= x0;
  x0 += x1; x1 = rotl32(x1, 6); x1 ^= x0;
  x0 += k1; x1 += ks2 + 1u;
  x0 += x1; x1 = rotl32(x1,17); x1 ^= x0;
  x0 += x1; x1 = rotl32(x1,29); x1 ^= x0;
  x0 += x1; x1 = rotl32(x1,16); x1 ^= x0;
  x0 += x1; x1 = rotl32(x1,24); x1 ^= x0;
  x0 += ks2; x1 += k0 + 2u;
  x0 += x1; x1 = rotl32(x1,13); x1 ^= x0;
  x0 += x1; x1 = rotl32(x1,15); x1 ^= x0;
  x0 += x1; x1 = rotl32(x1,26); x1 ^= x0;
  x0 += x1; x1 = rotl32(x1, 6); x1 ^= x0;
  x0 += k0; x1 += k1 + 3u;
  x0 += x1; x1 = rotl32(x1,17); x1 ^= x0;
  x0 += x1; x1 = rotl32(x1,29); x1 ^= x0;
  x0 += x1; x1 = rotl32(x1,16); x1 ^= x0;
  x0 += x1; x1 = rotl32(x1,24); x1 ^= x0;
  x0 += k1; x1 += ks2 + 4u;
  x0 += x1; x1 = rotl32(x1,13); x1 ^= x0;
  x0 += x1; x1 = rotl32(x1,15); x1 ^= x0;
  x0 += x1; x1 = rotl32(x1,26); x1 ^= x0;
  x0 += x1; x1 = rotl32(x1, 6); x1 ^= x0;
  x0 += ks2; x1 += k0 + 5u;
  *o0 = x0; *o1 = x1;
}

// ---------------- helpers ----------------
__device__ inline float dot_f4(const float* __restrict__ a, const float* __restrict__ w, int K){
  float acc = 0.f;
  const float4* a4 = (const float4*)a;
  const float4* w4 = (const float4*)w;
  int K4 = K >> 2;
  for (int k = 0; k < K4; ++k){
    float4 av = a4[k], wv = w4[k];
    acc = fmaf(av.x, wv.x, acc);
    acc = fmaf(av.y, wv.y, acc);
    acc = fmaf(av.z, wv.z, acc);
    acc = fmaf(av.w, wv.w, acc);
  }
  return acc;
}

// LayerNorm across a 512-thread block (one value per thread).
__device__ inline float block_ln(float v, float g, float bb, float* red){
  __syncthreads();
  float s = v;
  #pragma unroll
  for (int off = 32; off; off >>= 1) s += __shfl_xor(s, off);
  if ((threadIdx.x & 63) == 0) red[threadIdx.x >> 6] = s;
  __syncthreads();
  float mu = (red[0]+red[1]+red[2]+red[3]+red[4]+red[5]+red[6]+red[7]) * (1.0f/512.0f);
  float dv = v - mu;
  float sq = dv * dv;
  #pragma unroll
  for (int off = 32; off; off >>= 1) sq += __shfl_xor(sq, off);
  __syncthreads();
  if ((threadIdx.x & 63) == 0) red[threadIdx.x >> 6] = sq;
  __syncthreads();
  float var = (red[0]+red[1]+red[2]+red[3]+red[4]+red[5]+red[6]+red[7]) * (1.0f/512.0f);
  return dv * (1.0f / sqrtf(var + 1e-5f)) * g + bb;
}

// row reduction among the 128 threads (2 waves) owning row j; all 512 threads call.
__device__ inline float row_reduce(float v, int wid, int j, float* wred){
  #pragma unroll
  for (int off = 32; off; off >>= 1) v += __shfl_xor(v, off);
  if ((threadIdx.x & 63) == 0) wred[wid] = v;
  __syncthreads();
  float r = wred[2*j] + wred[2*j+1];
  __syncthreads();
  return r;
}

// ---------------- group barrier: 32 blocks of group g ----------------
__device__ __forceinline__ void gbar(unsigned* bar, int g){
  __syncthreads();
  if (threadIdx.x == 0){
    unsigned* cnt = bar + g*64;
    unsigned* gen = bar + g*64 + 16;
    __builtin_amdgcn_fence(__ATOMIC_RELEASE, "agent");
    unsigned old = __hip_atomic_load(gen, __ATOMIC_RELAXED, __HIP_MEMORY_SCOPE_AGENT);
    if (__hip_atomic_fetch_add(cnt, 1u, __ATOMIC_RELAXED, __HIP_MEMORY_SCOPE_AGENT) == 31u){
      __hip_atomic_store(cnt, 0u, __ATOMIC_RELAXED, __HIP_MEMORY_SCOPE_AGENT);
      __hip_atomic_fetch_add(gen, 1u, __ATOMIC_RELEASE, __HIP_MEMORY_SCOPE_AGENT);
    } else {
      while (__hip_atomic_load(gen, __ATOMIC_RELAXED, __HIP_MEMORY_SCOPE_AGENT) == old)
        __builtin_amdgcn_s_sleep(1);
    }
    __builtin_amdgcn_fence(__ATOMIC_ACQUIRE, "agent");
  }
  __syncthreads();
}

// ---------------- setup kernels ----------------
__global__ void k_tables(float* __restrict__ cosb, float* __restrict__ sinb){
  int tid = blockIdx.x * blockDim.x + threadIdx.x;  // TT*256
  int p = tid >> 8, i = tid & 255;
  float sv = (2.0f * (float)i + 204.8f) / 716.8f;
  float scale = powf(sv, (float)p / 16.0f);
  float invf = 1.0f / powf(10000.0f, (float)i / 256.0f);
  float ang = (float)p * invf;
  cosb[tid] = cosf(ang) * scale;
  sinb[tid] = sinf(ang) * scale;
}

__global__ void k_ca1(const float* __restrict__ mol, const float* __restrict__ w,
                      const float* __restrict__ bias, float* __restrict__ tmp){
  int tid = blockIdx.x * blockDim.x + threadIdx.x;  // LL*BB*DD
  int l = tid >> 14; int r = tid & 16383; int b = r >> 9; int d = r & 511;
  const float* wr = w + (size_t)l*3*DD*DD + (size_t)(2*DD + d)*DD;
  tmp[tid] = bias[l*3*DD + 2*DD + d] + dot_f4(mol + (size_t)b*DD, wr, DD);
}

__global__ void k_ca2(const float* __restrict__ tmp, const float* __restrict__ w,
                      const float* __restrict__ bias, float* __restrict__ cac){
  int tid = blockIdx.x * blockDim.x + threadIdx.x;  // LL*BB*DD
  int l = tid >> 14; int r = tid & 16383; int b = r >> 9; int d = r & 511;
  const float* wr = w + (size_t)l*DD*DD + (size_t)d*DD;
  cac[tid] = bias[l*DD + d] + dot_f4(tmp + ((size_t)l*BB + b)*DD, wr, DD);
}

__global__ void k_binit(unsigned* __restrict__ bar, int* __restrict__ pred){
  int tid = threadIdx.x;            // 1024 threads
  bar[tid] = 0u;
  pred[tid]        = ((tid & (TT-1)) == 0) ? 1 : 0;
  pred[tid + 1024] = (((tid + 1024) & (TT-1)) == 0) ? 1 : 0;
}

// k32-pack: in [L][N][K] row-major -> out [L][K/32][N][32]
// out[((l*(K/32)+k32)*N + n)*32 + ku] = in[l][n][k32*32+ku]; one 128B line per (k32,n).
__global__ void k_pack32(const float* __restrict__ in, float* __restrict__ out,
                         int N, int K, int total){
  int tid = blockIdx.x * blockDim.x + threadIdx.x;
  if (tid >= total) return;
  int S = N * K;
  int l = tid / S, r = tid - l*S;
  int k32 = r / (32*N);
  int r2 = r - k32*32*N;
  int n = r2 >> 5, ku = r2 & 31;
  out[tid] = in[(size_t)l*S + (size_t)n*K + k32*32 + ku];
}

// consume one cell (8 float4 = 32 k) into 4 row accumulators, k-ascending
#define CELL4(WARR, KOFF)                                                     \
  _Pragma("unroll")                                                           \
  for (int q = 0; q < 8; ++q){                                                \
    float4 w = WARR[q];                                                       \
    const int kk = (KOFF) + q*4;                                              \
    float4 xa = *(const float4*)&sxp[0*512 + kk];                             \
    float4 xb = *(const float4*)&sxp[1*512 + kk];                             \
    float4 xc = *(const float4*)&sxp[2*512 + kk];                             \
    float4 xd = *(const float4*)&sxp[3*512 + kk];                             \
    a0=fmaf(w.x,xa.x,a0); a0=fmaf(w.y,xa.y,a0); a0=fmaf(w.z,xa.z,a0); a0=fmaf(w.w,xa.w,a0); \
    a1=fmaf(w.x,xb.x,a1); a1=fmaf(w.y,xb.y,a1); a1=fmaf(w.z,xb.z,a1); a1=fmaf(w.w,xb.w,a1); \
    a2=fmaf(w.x,xc.x,a2); a2=fmaf(w.y,xc.y,a2); a2=fmaf(w.z,xc.z,a2); a2=fmaf(w.w,xc.w,a2); \
    a3=fmaf(w.x,xd.x,a3); a3=fmaf(w.y,xd.y,a3); a3=fmaf(w.z,xd.z,a3); a3=fmaf(w.w,xd.w,a3); \
  }

// ---------------- persistent decode kernel ----------------
struct KParams {
  const float *emb, *sab, *sob, *f1b, *f2b;
  const float *g1,*b1,*g2,*b2,*g3,*b3,*fg,*fb;
  const float *o1b,*o2b,*o3w,*o3b;
  const float *cosb,*sinb,*cac;
  const float *sawP,*sowP,*f1wP,*f2wP,*o1wP,*o2wP;   // k32-packed [K/32][N][32]
  float *kc,*vc,*xl,*qb,*at,*ao,*x2,*fo,*h1,*xf,*hh1,*hh2,*ps3;
  int *pred;
  unsigned *bar;
};

__global__ __launch_bounds__(NTHR) void k_persist(KParams P){
  const int bid = blockIdx.x, tid = threadIdx.x;
  const int g = bid & 7;          // group (XCD-aligned under %8 round-robin; perf hint only)
  const int m = bid >> 3;         // member 0..31
  const int wid = tid >> 6, lane = tid & 63;
  __shared__ __align__(16) float smem[8704];

  for (int t = 1; t < TT; ++t){
    const int pp = t - 1;

    for (int l = 0; l < LL; ++l){
      // ================= S1: build x_l + QKV (24 blocks n-sliced) =================
      {
        float* sx   = smem;          // [4][512]
        float* part = smem + 2048;   // [8][4][64]
        float* srow = smem + 4096;   // [4][2]
        const int j = tid >> 7, d4 = (tid & 127) * 4;
        const int rb = g*4 + j;
        if (l == 0){
          int tok = P.pred[rb*TT + pp];
          #pragma unroll
          for (int e = d4; e < d4 + 4; e += 2){
            int i = e >> 1;
            float c = P.cosb[pp*256 + i], s = P.sinb[pp*256 + i];
            float e0 = P.emb[(size_t)tok*DD + e];
            float e1 = P.emb[(size_t)tok*DD + e + 1];
            sx[j*512 + e]     = fmaf(e0, c, -(e1*s));
            sx[j*512 + e + 1] = fmaf(e1, c, e0*s);
          }
        } else {
          if (tid < 4){
            float a = 0.f, bq = 0.f;
            const float* pr = P.ps3 + (size_t)(g*4 + tid)*64;
            for (int s = 0; s < 32; ++s){ a += pr[s*2]; bq += pr[s*2+1]; }
            float mu = a * (1.0f/512.0f);
            float var = bq * (1.0f/512.0f) - mu*mu;
            srow[tid*2]   = mu;
            srow[tid*2+1] = 1.0f / sqrtf(var + 1e-5f);
          }
          __syncthreads();
          float mu = srow[j*2], rs = srow[j*2+1];
          float4 xv = *(const float4*)&P.x2[(size_t)rb*DD + d4];
          float4 fv = *(const float4*)&P.fo[(size_t)rb*DD + d4];
          const float* g3r = P.g3 + (size_t)(l-1)*DD;
          const float* b3r = P.b3 + (size_t)(l-1)*DD;
          float yv[4] = {xv.x+fv.x, xv.y+fv.y, xv.z+fv.z, xv.w+fv.w};
          #pragma unroll
          for (int i = 0; i < 4; ++i)
            sx[j*512 + d4 + i] = (yv[i]-mu)*rs*g3r[d4+i] + b3r[d4+i];
        }
        __syncthreads();
        if (m == 0){   // materialize x_l
          float4 v = *(float4*)&sx[j*512 + d4];
          *(float4*)&P.xl[(size_t)rb*DD + d4] = v;
        }
        if (m < 24){
          const int n0 = m*64;
          const float4* wb0 = (const float4*)P.sawP + ((size_t)l*16 + wid*2)*(1536*8)
                            + (size_t)(n0 + lane)*8;
          const float4* wb1 = wb0 + 1536*8;
          float4 w0[8], w1[8];
          #pragma unroll
          for (int q = 0; q < 8; ++q) w0[q] = wb0[q];
          #pragma unroll
          for (int q = 0; q < 8; ++q) w1[q] = wb1[q];
          float a0=0.f,a1=0.f,a2=0.f,a3=0.f;
          const float* sxp = sx;
          const int kb = wid*64;
          CELL4(w0, kb);
          CELL4(w1, kb + 32);
          part[(wid*4+0)*64 + lane] = a0;
          part[(wid*4+1)*64 + lane] = a1;
          part[(wid*4+2)*64 + lane] = a2;
          part[(wid*4+3)*64 + lane] = a3;
          __syncthreads();
          if (tid < 256){
            int jr = tid >> 6, nl = tid & 63;
            int n = n0 + nl, rb2 = g*4 + jr;
            float s = P.sab[l*1536 + n];
            #pragma unroll
            for (int w = 0; w < 8; ++w) s += part[(w*4+jr)*64 + nl];
            if (n < DD){
              P.qb[(size_t)rb2*DD + n] = s;
            } else if (n < 2*DD){
              int h = (n - DD) >> 6, hd = (n - DD) & 63;
              P.kc[((((size_t)l*BB + rb2)*HH + h)*TT + pp)*HDIM + hd] = s;
            } else {
              int h = (n - 2*DD) >> 6, hd = (n - 2*DD) & 63;
              P.vc[((((size_t)l*BB + rb2)*HH + h)*TT + pp)*HDIM + hd] = s;
            }
          }
        }
      }
      gbar(P.bar, g);

      // ================= S2: attention (32 blocks = (row,head), 1 wave) =================
      {
        int bl = m >> 3, h = m & 7, rb = g*4 + bl;
        float* qs = smem; float* ps = smem + 64;
        if (tid < 64) qs[tid] = P.qb[(size_t)rb*DD + h*HDIM + tid];
        __syncthreads();
        if (tid < 64){
          const float* kb = P.kc + (((size_t)l*BB + rb)*HH + h)*TT*HDIM;
          float s = -INFINITY;
          if (lane <= pp && P.pred[rb*TT + lane] != 0){
            const float* kr = kb + lane*HDIM;
            float acc = 0.f;
            #pragma unroll
            for (int k2 = 0; k2 < HDIM; ++k2) acc = fmaf(qs[k2], kr[k2], acc);
            s = acc * 0.125f;
          }
          float mx = s;
          #pragma unroll
          for (int off = 32; off; off >>= 1) mx = fmaxf(mx, __shfl_xor(mx, off));
          float e = (s == -INFINITY) ? 0.f : expf(s - mx);
          float sum = e;
          #pragma unroll
          for (int off = 32; off; off >>= 1) sum += __shfl_xor(sum, off);
          ps[lane] = e / sum;
          const float* vb = P.vc + (((size_t)l*BB + rb)*HH + h)*TT*HDIM;
          float o = 0.f;
          int jj = 0;
          for (; jj + 8 <= t; jj += 8){
            float vv[8];
            #pragma unroll
            for (int u = 0; u < 8; ++u) vv[u] = vb[(jj+u)*HDIM + lane];
            #pragma unroll
            for (int u = 0; u < 8; ++u) o = fmaf(ps[jj+u], vv[u], o);
          }
          for (; jj <= pp; ++jj) o = fmaf(ps[jj], vb[jj*HDIM + lane], o);
          P.at[(size_t)rb*DD + h*HDIM + lane] = o;
        }
      }
      gbar(P.bar, g);

      // ================= S3: oproj (32 blocks, 16 cols each) =================
      {
        float* ats  = smem;          // [4][512]
        float* part = smem + 2048;   // [8][64]
        const int j = tid >> 7, d4 = (tid & 127) * 4;
        *(float4*)&ats[j*512 + d4] = *(const float4*)&P.at[(size_t)(g*4+j)*DD + d4];
        __syncthreads();
        const int n0 = m*16;
        const int jb = lane >> 4, nc = lane & 15;
        const float4* wb0 = (const float4*)P.sowP + ((size_t)l*16 + wid*2)*(512*8)
                          + (size_t)(n0 + nc)*8;
        const float4* wb1 = wb0 + 512*8;
        float4 w0[8], w1[8];
        #pragma unroll
        for (int q = 0; q < 8; ++q) w0[q] = wb0[q];
        #pragma unroll
        for (int q = 0; q < 8; ++q) w1[q] = wb1[q];
        float acc = 0.f;
        const int kb = wid*64;
        #pragma unroll
        for (int q = 0; q < 8; ++q){
          float4 w = w0[q];
          float4 xa = *(const float4*)&ats[jb*512 + kb + q*4];
          acc=fmaf(w.x,xa.x,acc); acc=fmaf(w.y,xa.y,acc); acc=fmaf(w.z,xa.z,acc); acc=fmaf(w.w,xa.w,acc);
        }
        #pragma unroll
        for (int q = 0; q < 8; ++q){
          float4 w = w1[q];
          float4 xa = *(const float4*)&ats[jb*512 + kb + 32 + q*4];
          acc=fmaf(w.x,xa.x,acc); acc=fmaf(w.y,xa.y,acc); acc=fmaf(w.z,xa.z,acc); acc=fmaf(w.w,xa.w,acc);
        }
        part[wid*64 + lane] = acc;
        __syncthreads();
        if (tid < 64){
          int jb2 = tid >> 4, nc2 = tid & 15, n = n0 + nc2;
          float s = P.sob[l*DD + n];
          #pragma unroll
          for (int w = 0; w < 8; ++w) s += part[w*64 + jb2*16 + nc2];
          P.ao[(size_t)(g*4+jb2)*DD + n] = s;
        }
      }
      gbar(P.bar, g);

      // ================= S4: ln1+ln2 (redundant) + FF1 (32 blocks, 64 cols) =================
      {
        float* sx2  = smem;          // [4][512]
        float* part = smem + 2048;   // [8][4][64]
        float* wred = smem + 4096;   // [8]
        const int j = tid >> 7, d4 = (tid & 127) * 4;
        const int rb = g*4 + j;
        float4 xlv = *(const float4*)&P.xl[(size_t)rb*DD + d4];
        float4 aov = *(const float4*)&P.ao[(size_t)rb*DD + d4];
        float y[4] = {xlv.x+aov.x, xlv.y+aov.y, xlv.z+aov.z, xlv.w+aov.w};
        float s = ((y[0]+y[1])+y[2])+y[3];
        float mu = row_reduce(s, wid, j, wred) * (1.0f/512.0f);
        float dv[4], sq = 0.f;
        #pragma unroll
        for (int i = 0; i < 4; ++i){ dv[i] = y[i]-mu; sq += dv[i]*dv[i]; }
        float rs = 1.0f / sqrtf(row_reduce(sq, wid, j, wred) * (1.0f/512.0f) + 1e-5f);
        float z[4];
        #pragma unroll
        for (int i = 0; i < 4; ++i){
          int d = d4 + i;
          z[i] = dv[i]*rs*P.g1[l*DD+d] + P.b1[l*DD+d] + P.cac[((size_t)l*BB + rb)*DD + d];
        }
        float s2 = ((z[0]+z[1])+z[2])+z[3];
        float mu2 = row_reduce(s2, wid, j, wred) * (1.0f/512.0f);
        float dz[4], sq2 = 0.f;
        #pragma unroll
        for (int i = 0; i < 4; ++i){ dz[i] = z[i]-mu2; sq2 += dz[i]*dz[i]; }
        float rs2 = 1.0f / sqrtf(row_reduce(sq2, wid, j, wred) * (1.0f/512.0f) + 1e-5f);
        float x2v[4];
        #pragma unroll
        for (int i = 0; i < 4; ++i){
          int d = d4 + i;
          x2v[i] = dz[i]*rs2*P.g2[l*DD+d] + P.b2[l*DD+d];
          sx2[j*512 + d] = x2v[i];
        }
        if (m == 0) *(float4*)&P.x2[(size_t)rb*DD + d4] = make_float4(x2v[0],x2v[1],x2v[2],x2v[3]);
        __syncthreads();
        // ff1 dot (k32-packed, 16 loads then consume)
        const int n0 = m*64;
        const float4* wb0 = (const float4*)P.f1wP + ((size_t)l*16 + wid*2)*(2048*8)
                          + (size_t)(n0 + lane)*8;
        const float4* wb1 = wb0 + 2048*8;
        float4 w0[8], w1[8];
        #pragma unroll
        for (int q = 0; q < 8; ++q) w0[q] = wb0[q];
        #pragma unroll
        for (int q = 0; q < 8; ++q) w1[q] = wb1[q];
        float a0=0.f,a1=0.f,a2=0.f,a3=0.f;
        const float* sxp = sx2;
        const int kb = wid*64;
        CELL4(w0, kb);
        CELL4(w1, kb + 32);
        part[(wid*4+0)*64 + lane] = a0;
        part[(wid*4+1)*64 + lane] = a1;
        part[(wid*4+2)*64 + lane] = a2;
        part[(wid*4+3)*64 + lane] = a3;
        __syncthreads();
        if (tid < 256){
          int jr = tid >> 6, nl = tid & 63;
          int n = n0 + nl;
          float v = P.f1b[l*FFD + n];
          #pragma unroll
          for (int w = 0; w < 8; ++w) v += part[(w*4+jr)*64 + nl];
          P.h1[(size_t)(g*4+jr)*FFD + n] = v / (1.0f + expf(-v));
        }
      }
      gbar(P.bar, g);

      // ================= S5: FF2 (32 blocks, 16 cols) + ln3 partials =================
      {
        float* sh1  = smem;          // [4][2048]
        float* part = smem + 8192;   // [8][64]
        #pragma unroll
        for (int q = 0; q < 4; ++q){
          int fi = tid + q*512;               // float4 index over [4][512]
          int j = fi >> 9, c4 = fi & 511;
          *(float4*)&sh1[j*2048 + c4*4] = *(const float4*)&P.h1[(size_t)(g*4+j)*FFD + c4*4];
        }
        __syncthreads();
        const int n0 = m*16;
        const int jb = lane >> 4, nc = lane & 15;
        const float4* base = (const float4*)P.f2wP + ((size_t)l*64 + wid*8)*(512*8)
                           + (size_t)(n0 + nc)*8;
        float acc = 0.f;
        #pragma unroll
        for (int cc = 0; cc < 4; ++cc){
          const float4* b0 = base + (size_t)(cc*2)*(512*8);
          const float4* b1 = b0 + 512*8;
          float4 w0[8], w1[8];
          #pragma unroll
          for (int q = 0; q < 8; ++q) w0[q] = b0[q];
          #pragma unroll
          for (int q = 0; q < 8; ++q) w1[q] = b1[q];
          const int kb = wid*256 + cc*64;
          #pragma unroll
          for (int q = 0; q < 8; ++q){
            float4 w = w0[q];
            float4 xa = *(const float4*)&sh1[jb*2048 + kb + q*4];
            acc=fmaf(w.x,xa.x,acc); acc=fmaf(w.y,xa.y,acc); acc=fmaf(w.z,xa.z,acc); acc=fmaf(w.w,xa.w,acc);
          }
          #pragma unroll
          for (int q = 0; q < 8; ++q){
            float4 w = w1[q];
            float4 xa = *(const float4*)&sh1[jb*2048 + kb + 32 + q*4];
            acc=fmaf(w.x,xa.x,acc); acc=fmaf(w.y,xa.y,acc); acc=fmaf(w.z,xa.z,acc); acc=fmaf(w.w,xa.w,acc);
          }
        }
        part[wid*64 + lane] = acc;
        __syncthreads();
        if (tid < 64){
          int jb2 = tid >> 4, nc2 = tid & 15, n = n0 + nc2;
          int rb2 = g*4 + jb2;
          float val = P.f2b[l*DD + n];
          #pragma unroll
          for (int w = 0; w < 8; ++w) val += part[w*64 + jb2*16 + nc2];
          P.fo[(size_t)rb2*DD + n] = val;
          float y = P.x2[(size_t)rb2*DD + n] + val;
          float s1 = y, sq = y*y;
          #pragma unroll
          for (int off = 1; off < 16; off <<= 1){
            s1 += __shfl_xor(s1, off);
            sq += __shfl_xor(sq, off);
          }
          if (nc2 == 0){
            P.ps3[(size_t)(rb2*32 + m)*2]     = s1;
            P.ps3[(size_t)(rb2*32 + m)*2 + 1] = sq;
          }
        }
      }
      gbar(P.bar, g);
    }

    // ================= S6: final ln3 + fn ln (4 row blocks) =================
    if (m < 4){
      int rb = g*4 + m, d = tid;
      float y = P.x2[(size_t)rb*DD + d] + P.fo[(size_t)rb*DD + d];
      float xv = block_ln(y, P.g3[3*DD + d], P.b3[3*DD + d], smem);
      float o  = block_ln(xv, P.fg[d], P.fb[d], smem);
      P.xf[(size_t)rb*DD + d] = o;
    }
    gbar(P.bar, g);

    // ================= S7: head1 (32 blocks, 32 cols) =================
    {
      float* sxf  = smem;          // [4][512]
      float* part = smem + 2048;   // [8][2][64]
      const int j = tid >> 7, d4 = (tid & 127) * 4;
      *(float4*)&sxf[j*512 + d4] = *(const float4*)&P.xf[(size_t)(g*4+j)*DD + d4];
      __syncthreads();
      const int n0 = m*32;
      const int jh = lane >> 5, nc = lane & 31;
      const float4* wb0 = (const float4*)P.o1wP + (size_t)(wid*2)*(1024*8)
                        + (size_t)(n0 + nc)*8;
      const float4* wb1 = wb0 + 1024*8;
      float4 w0[8], w1[8];
      #pragma unroll
      for (int q = 0; q < 8; ++q) w0[q] = wb0[q];
      #pragma unroll
      for (int q = 0; q < 8; ++q) w1[q] = wb1[q];
      float ac0 = 0.f, ac1 = 0.f;
      const int kb = wid*64;
      #pragma unroll
      for (int q = 0; q < 8; ++q){
        float4 w = w0[q];
        float4 xa = *(const float4*)&sxf[jh*512 + kb + q*4];
        float4 xb = *(const float4*)&sxf[(jh+2)*512 + kb + q*4];
        ac0=fmaf(w.x,xa.x,ac0); ac0=fmaf(w.y,xa.y,ac0); ac0=fmaf(w.z,xa.z,ac0); ac0=fmaf(w.w,xa.w,ac0);
        ac1=fmaf(w.x,xb.x,ac1); ac1=fmaf(w.y,xb.y,ac1); ac1=fmaf(w.z,xb.z,ac1); ac1=fmaf(w.w,xb.w,ac1);
      }
      #pragma unroll
      for (int q = 0; q < 8; ++q){
        float4 w = w1[q];
        float4 xa = *(const float4*)&sxf[jh*512 + kb + 32 + q*4];
        float4 xb = *(const float4*)&sxf[(jh+2)*512 + kb + 32 + q*4];
        ac0=fmaf(w.x,xa.x,ac0); ac0=fmaf(w.y,xa.y,ac0); ac0=fmaf(w.z,xa.z,ac0); ac0=fmaf(w.w,xa.w,ac0);
        ac1=fmaf(w.x,xb.x,ac1); ac1=fmaf(w.y,xb.y,ac1); ac1=fmaf(w.z,xb.z,ac1); ac1=fmaf(w.w,xb.w,ac1);
      }
      part[(wid*2+0)*64 + lane] = ac0;
      part[(wid*2+1)*64 + lane] = ac1;
      __syncthreads();
      if (tid < 128){
        int row = tid >> 5, nc2 = tid & 31;
        int r = row >> 1, jh2 = row & 1;
        float s = P.o1b[n0 + nc2];
        #pragma unroll
        for (int w = 0; w < 8; ++w) s += part[(w*2+r)*64 + jh2*32 + nc2];
        float a = s;
        P.hh1[(size_t)(g*4+row)*1024 + n0 + nc2] = 0.5f * a * (1.0f + erff(a / 1.41421356237309504880f));
      }
    }
    gbar(P.bar, g);

    // ================= S8: head2 (32 blocks, 32 cols, K=1024) =================
    {
      float* sh   = smem;          // [4][1024]
      float* part = smem + 4096;   // [8][2][64]
      #pragma unroll
      for (int q = 0; q < 2; ++q){
        int fi = tid + q*512;               // float4 index over [4][256]
        int j = fi >> 8, c4 = fi & 255;
        *(float4*)&sh[j*1024 + c4*4] = *(const float4*)&P.hh1[(size_t)(g*4+j)*1024 + c4*4];
      }
      __syncthreads();
      const int n0 = m*32;
      const int jh = lane >> 5, nc = lane & 31;
      const float4* base = (const float4*)P.o2wP + (size_t)(wid*4)*(1024*8)
                         + (size_t)(n0 + nc)*8;
      float ac0 = 0.f, ac1 = 0.f;
      #pragma unroll
      for (int cc = 0; cc < 2; ++cc){
        const float4* b0 = base + (size_t)(cc*2)*(1024*8);
        const float4* b1 = b0 + 1024*8;
        float4 w0[8], w1[8];
        #pragma unroll
        for (int q = 0; q < 8; ++q) w0[q] = b0[q];
        #pragma unroll
        for (int q = 0; q < 8; ++q) w1[q] = b1[q];
        const int kb = wid*128 + cc*64;
        #pragma unroll
        for (int q = 0; q < 8; ++q){
          float4 w = w0[q];
          float4 xa = *(const float4*)&sh[jh*1024 + kb + q*4];
          float4 xb = *(const float4*)&sh[(jh+2)*1024 + kb + q*4];
          ac0=fmaf(w.x,xa.x,ac0); ac0=fmaf(w.y,xa.y,ac0); ac0=fmaf(w.z,xa.z,ac0); ac0=fmaf(w.w,xa.w,ac0);
          ac1=fmaf(w.x,xb.x,ac1); ac1=fmaf(w.y,xb.y,ac1); ac1=fmaf(w.z,xb.z,ac1); ac1=fmaf(w.w,xb.w,ac1);
        }
        #pragma unroll
        for (int q = 0; q < 8; ++q){
          float4 w = w1[q];
          float4 xa = *(const float4*)&sh[jh*1024 + kb + 32 + q*4];
          float4 xb = *(const float4*)&sh[(jh+2)*1024 + kb + 32 + q*4];
          ac0=fmaf(w.x,xa.x,ac0); ac0=fmaf(w.y,xa.y,ac0); ac0=fmaf(w.z,xa.z,ac0); ac0=fmaf(w.w,xa.w,ac0);
          ac1=fmaf(w.x,xb.x,ac1); ac1=fmaf(w.y,xb.y,ac1); ac1=fmaf(w.z,xb.z,ac1); ac1=fmaf(w.w,xb.w,ac1);
        }
      }
      part[(wid*2+0)*64 + lane] = ac0;
      part[(wid*2+1)*64 + lane] = ac1;
      __syncthreads();
      if (tid < 128){
        int row = tid >> 5, nc2 = tid & 31;
        int r = row >> 1, jh2 = row & 1;
        float s = P.o2b[n0 + nc2];
        #pragma unroll
        for (int w = 0; w < 8; ++w) s += part[(w*2+r)*64 + jh2*32 + nc2];
        float a = s;
        P.hh2[(size_t)(g*4+row)*1024 + n0 + nc2] = 0.5f * a * (1.0f + erff(a / 1.41421356237309504880f));
      }
    }
    gbar(P.bar, g);

    // ================= S9: sample (4 row blocks; exact r5 math) =================
    if (m < 4){
      int rb = g*4 + m, v = tid;
      float* hrow = smem;                 // 1024
      float* red  = smem + 1024;          // 8
      int*   redi = (int*)(smem + 1032);  // 2
      for (int k = tid; k < 1024; k += NTHR) hrow[k] = P.hh2[(size_t)rb*1024 + k];
      __syncthreads();
      float sv = 0.f;
      if (tid < 128){
        float acc = P.o3b[v] + dot_f4(hrow, P.o3w + (size_t)v*1024, 1024);
        sv = acc / 0.1f;
      }
      float mx = (tid < 128) ? sv : -INFINITY;
      #pragma unroll
      for (int off = 32; off; off >>= 1) mx = fmaxf(mx, __shfl_xor(mx, off));
      __syncthreads();
      if (tid < 128 && (tid & 63) == 0) red[tid >> 6] = mx;
      __syncthreads();
      mx = fmaxf(red[0], red[1]);
      float e = (tid < 128) ? expf(sv - mx) : 0.f;
      float sum = e;
      #pragma unroll
      for (int off = 32; off; off >>= 1) sum += __shfl_xor(sum, off);
      __syncthreads();
      if (tid < 128 && (tid & 63) == 0) red[tid >> 6] = sum;
      __syncthreads();
      sum = red[0] + red[1];
      float bv = -INFINITY; int bi = 0x7fffffff;
      if (tid < 128){
        float lp = (sv - mx) - logf(sum);
        uint32_t kk0, kk1, o0, o1;
        tf2x32(0u, 1u, 0u, (uint32_t)t, &kk0, &kk1);
        tf2x32(kk0, kk1, 0u, (uint32_t)(rb*VV + v), &o0, &o1);
        uint32_t bits = o0 ^ o1;
        float u = __uint_as_float((bits >> 9) | 0x3F800000u) - 1.0f;
        float gg = -logf(-logf(u + 1e-9f) + 1e-9f);
        bv = lp + gg; bi = v;
      }
      #pragma unroll
      for (int off = 32; off; off >>= 1){
        float ov = __shfl_xor(bv, off);
        int   oi = __shfl_xor(bi, off);
        if (ov > bv || (ov == bv && oi < bi)){ bv = ov; bi = oi; }
      }
      __syncthreads();
      if (tid < 128 && (tid & 63) == 0){ red[tid >> 6] = bv; redi[tid >> 6] = bi; }
      __syncthreads();
      if (tid == 0){
        float v0 = red[0], v1 = red[1]; int i0 = redi[0], i1 = redi[1];
        P.pred[rb*TT + t] = (v1 > v0 || (v1 == v0 && i1 < i0)) ? i1 : i0;
      }
    }
    gbar(P.bar, g);
  }
}

// ---------------- host ----------------
extern "C" void kernel_launch(void* const* d_in, const int* in_sizes, int n_in,
                              void* d_out, int out_size, void* d_ws, size_t ws_size,
                              hipStream_t stream){
  (void)in_sizes; (void)n_in; (void)out_size; (void)ws_size;
  const float* mol      = (const float*)d_in[1];
  const float* sa_in_w  = (const float*)d_in[3];
  const float* sa_out_w = (const float*)d_in[5];
  const float* ca_in_w  = (const float*)d_in[7];
  const float* ca_in_b  = (const float*)d_in[8];
  const float* ca_out_w = (const float*)d_in[9];
  const float* ca_out_b = (const float*)d_in[10];
  const float* ff_w1    = (const float*)d_in[11];
  const float* ff_w2    = (const float*)d_in[13];
  const float* out_w1   = (const float*)d_in[23];
  const float* out_w2   = (const float*)d_in[25];

  KParams P;
  P.emb = (const float*)d_in[2];
  P.sab = (const float*)d_in[4];
  P.sob = (const float*)d_in[6];
  P.f1b = (const float*)d_in[12];
  P.f2b = (const float*)d_in[14];
  P.g1  = (const float*)d_in[15];
  P.b1  = (const float*)d_in[16];
  P.g2  = (const float*)d_in[17];
  P.b2  = (const float*)d_in[18];
  P.g3  = (const float*)d_in[19];
  P.b3  = (const float*)d_in[20];
  P.fg  = (const float*)d_in[21];
  P.fb  = (const float*)d_in[22];
  P.o1b = (const float*)d_in[24];
  P.o2b = (const float*)d_in[26];
  P.o3w = (const float*)d_in[27];
  P.o3b = (const float*)d_in[28];

  unsigned* bar = (unsigned*)d_ws;          // 1024 uints
  float* ws = (float*)d_ws + 1024;
  float* cosb   = ws;                       // 16384
  float* sinb   = cosb + 16384;             // 16384
  float* ca_tmp = sinb + 16384;             // 65536
  float* cac    = ca_tmp + 65536;           // 65536
  float* kc     = cac + 65536;              // 4194304
  float* vc     = kc + 4194304;             // 4194304
  float* xl     = vc + 4194304;             // 16384
  float* qb     = xl + 16384;               // 16384
  float* at     = qb + 16384;               // 16384
  float* ao     = at + 16384;               // 16384
  float* x2     = ao + 16384;               // 16384
  float* fo     = x2 + 16384;               // 16384
  float* h1     = fo + 16384;               // 65536
  float* xf     = h1 + 65536;               // 16384
  float* hh1    = xf + 16384;               // 32768
  float* hh2    = hh1 + 32768;              // 32768
  float* ps3    = hh2 + 32768;              // 2048
  float* sawP   = ps3 + 2048;               // 3145728
  float* sowP   = sawP + 3145728;           // 1048576
  float* f1wP   = sowP + 1048576;           // 4194304
  float* f2wP   = f1wP + 4194304;           // 4194304
  float* o1wP   = f2wP + 4194304;           // 524288
  float* o2wP   = o1wP + 524288;            // 1048576

  P.cosb = cosb; P.sinb = sinb; P.cac = cac;
  P.kc = kc; P.vc = vc; P.xl = xl; P.qb = qb; P.at = at; P.ao = ao;
  P.x2 = x2; P.fo = fo; P.h1 = h1; P.xf = xf; P.hh1 = hh1; P.hh2 = hh2;
  P.ps3 = ps3;
  P.sawP = sawP; P.sowP = sowP; P.f1wP = f1wP; P.f2wP = f2wP;
  P.o1wP = o1wP; P.o2wP = o2wP;
  P.pred = (int*)d_out;
  P.bar = bar;

  k_binit<<<1, 1024, 0, stream>>>(bar, P.pred);
  k_tables<<<64, 256, 0, stream>>>(cosb, sinb);
  k_ca1<<<256, 256, 0, stream>>>(mol, ca_in_w, ca_in_b, ca_tmp);
  k_ca2<<<256, 256, 0, stream>>>(ca_tmp, ca_out_w, ca_out_b, cac);

  // k32-pack all streamed weights: [L][N][K] -> [L][K/32][N][32]
  {
    int t1 = 4*1536*512;  k_pack32<<<(t1+255)/256, 256, 0, stream>>>(sa_in_w,  sawP, 1536, 512,  t1);
    int t2 = 4*512*512;   k_pack32<<<(t2+255)/256, 256, 0, stream>>>(sa_out_w, sowP,  512, 512,  t2);
    int t3 = 4*2048*512;  k_pack32<<<(t3+255)/256, 256, 0, stream>>>(ff_w1,    f1wP, 2048, 512,  t3);
    int t4 = 4*512*2048;  k_pack32<<<(t4+255)/256, 256, 0, stream>>>(ff_w2,    f2wP,  512, 2048, t4);
    int t5 = 1024*512;    k_pack32<<<(t5+255)/256, 256, 0, stream>>>(out_w1,   o1wP, 1024, 512,  t5);
    int t6 = 1024*1024;   k_pack32<<<(t6+255)/256, 256, 0, stream>>>(out_w2,   o2wP, 1024, 1024, t6);
  }

  k_persist<<<NBLK, NTHR, 0, stream>>>(P);
}